// Round 9
// baseline (246.411 us; speedup 1.0000x reference)
//
#include <hip/hip_runtime.h>
#include <cstdint>

#define DEVI __device__ __forceinline__

typedef __bf16 bf16x8 __attribute__((ext_vector_type(8)));
typedef float  f32x4  __attribute__((ext_vector_type(4)));

template<int V> struct IC { static constexpr int v = V; };

DEVI unsigned short f2b(float f){
  unsigned u = __builtin_bit_cast(unsigned, f);
  unsigned r = u + 0x7FFF + ((u >> 16) & 1);
  return (unsigned short)(r >> 16);
}
DEVI float b2f(unsigned short s){
  unsigned u = ((unsigned)s) << 16;
  return __builtin_bit_cast(float, u);
}
DEVI float gelu_f(float x){
  float u = 0.7978845608028654f * (x + 0.044715f * x * x * x);
  float e = __expf(2.0f * u);
  return x * (1.0f - 1.0f / (e + 1.0f));   // == 0.5x(1+tanh(u)), safe at e->inf / e->0
}
DEVI void gl_lds16(const unsigned short* g, unsigned short* l){
  __builtin_amdgcn_global_load_lds(
      (const __attribute__((address_space(1))) unsigned int*)g,
      (__attribute__((address_space(3))) unsigned int*)l, 16, 0, 0);
}

// ---------------- weight transpose + fp32->bf16: in[R][C] f32 -> out[C][R] bf16 ----
__global__ __launch_bounds__(256)
void transpose_f2b(const float* __restrict__ in, unsigned short* __restrict__ out,
                   int R, int C)
{
  __shared__ float tile[32][33];
  int nbx = C >> 5;
  int bx = blockIdx.x % nbx, by = blockIdx.x / nbx;
  int c0 = bx << 5, r0 = by << 5;
  int tx = threadIdx.x & 31, ty = threadIdx.x >> 5;   // 32 x 8
  #pragma unroll
  for (int j = 0; j < 32; j += 8)
    tile[ty + j][tx] = in[(size_t)(r0 + ty + j) * C + c0 + tx];
  __syncthreads();
  #pragma unroll
  for (int j = 0; j < 32; j += 8)
    out[(size_t)(c0 + ty + j) * R + r0 + tx] = f2b(tile[tx][ty + j]);
}

// ---------------- RMSNorm: x f32 [rows][768] -> out bf16, 1 wave per row ----------
__global__ __launch_bounds__(256)
void rmsnorm_k(const float* __restrict__ x, const float* __restrict__ g,
               unsigned short* __restrict__ out)
{
  int wid = threadIdx.x >> 6, lane = threadIdx.x & 63;
  size_t row = (size_t)blockIdx.x * 4 + wid;
  const float* xr = x + row * 768;
  float4 v[3];
  float ss = 0.0f;
  #pragma unroll
  for (int c = 0; c < 3; c++){
    v[c] = *(const float4*)&xr[lane * 4 + c * 256];
    ss += v[c].x * v[c].x + v[c].y * v[c].y + v[c].z * v[c].z + v[c].w * v[c].w;
  }
  #pragma unroll
  for (int o = 32; o >= 1; o >>= 1) ss += __shfl_xor(ss, o);
  float rs = rsqrtf(ss * (1.0f / 768.0f) + 1e-6f);
  #pragma unroll
  for (int c = 0; c < 3; c++){
    const float4 gv = *(const float4*)&g[lane * 4 + c * 256];
    ushort4 o4;
    o4.x = f2b(v[c].x * rs * gv.x);
    o4.y = f2b(v[c].y * rs * gv.y);
    o4.z = f2b(v[c].z * rs * gv.z);
    o4.w = f2b(v[c].w * rs * gv.w);
    *(ushort4*)&out[row * 768 + lane * 4 + c * 256] = o4;
  }
}

// ---------------- GEMM 256x256, BK=64, 8 waves, phased + counted vmcnt(8) ---------
// C[M,N] = A[M,K](bf16) * Bt[N,K](bf16)^T, fused epilogue.
// 8 waves 2(M)x4(N); per-wave 128x64 (8 m-frags x 4 n-frags), acc = 128 VGPR.
// Fragment-read density Mf*Nf/(Mf+Nf) = 2.67 (vs 2.0 at 4x4): raises the LDS-BW
// MfmaUtil ceiling from ~36% to ~70% (the r5-r8 binding constraint).
// LDS = 2 x (A 256x64 + B 256x64) bf16 = 128 KiB, XOR slot swizzle (r5, proven).
// Pipeline: stage(t+1) fully at top of tile t -> vmcnt(8) waits ONLY for stage(t)
// (issued one full tile earlier, ~1200cy slack) -> barrier -> 4 phases of
// {ds_read A-pair (+B at p0) | barrier | lgkmcnt(0) | setprio+16 MFMA | barrier}.
// Race ledger: stage(t+1) writes buf^1, last read in tile t-1, fenced by the
// end-of-(t-1) phase barrier; reads of buf[t] fenced by per-wave vmcnt(8)+barrier.
// Requires M%256==0, N%256==0, K%128==0, grid%8==0.
template<bool BIAS, bool GELU_, bool OUTF32>
__global__ __launch_bounds__(512, 2)
void gemm256(const unsigned short* __restrict__ A, const unsigned short* __restrict__ Bt,
             const float* __restrict__ bias, void* __restrict__ outp,
             int M, int N, int K)
{
  __shared__ unsigned short sm[2][32768];   // [buf][ A: 0..16383 | B: 16384.. ]
  int tid = threadIdx.x, wid = tid >> 6, lane = tid & 63;
  int la = lane & 15, hi = lane >> 4;
  int wm = wid >> 2, wn = wid & 3;          // 2 x 4 waves, per-wave 128x64
  int tiles_n = N >> 8;
  int bid = blockIdx.x;
  bid = (bid & 7) * (gridDim.x >> 3) + (bid >> 3);   // XCD-aware swizzle
  int m0 = (bid / tiles_n) << 8, n0 = (bid % tiles_n) << 8;
  int NT = K >> 6;

  f32x4 acc[8][4] = {};

  // ---- hoisted stage addressing: per-thread 8 loads (4 A + 4 B)
  const unsigned short* aSrc[4];
  const unsigned short* bSrc[4];
  unsigned short* aDst[2][4];
  unsigned short* bDst[2][4];
  #pragma unroll
  for (int l = 0; l < 4; l++){
    int cb = l * 512 + wid * 64;            // 16B-slot index, wave-uniform base
    int idx = cb + lane;
    int row = idx >> 3, sl2 = (idx & 7) ^ (row & 7);
    aSrc[l] = A + (size_t)(m0 + row) * K + sl2 * 8;
    bSrc[l] = Bt + (size_t)(n0 + row) * K + sl2 * 8;
    aDst[0][l] = &sm[0][cb * 8];            aDst[1][l] = &sm[1][cb * 8];
    bDst[0][l] = &sm[0][16384 + cb * 8];    bDst[1][l] = &sm[1][16384 + cb * 8];
  }

  // ---- hoisted fragment bases [buf][kk] (XOR is lane-constant: row&7 == la&7)
  const unsigned short* fA[2][2];
  const unsigned short* fB[2][2];
  #pragma unroll
  for (int bf = 0; bf < 2; bf++)
    #pragma unroll
    for (int kk = 0; kk < 2; kk++){
      int sw = ((kk * 4 + hi) ^ (la & 7)) * 8;
      fA[bf][kk] = &sm[bf][(wm * 128 + la) * 64 + sw];
      fB[bf][kk] = &sm[bf][16384 + (wn * 64 + la) * 64 + sw];
    }

  auto stageTo = [&](auto BF){
    constexpr int bf = decltype(BF)::v;
    #pragma unroll
    for (int l = 0; l < 4; l++){ gl_lds16(aSrc[l], aDst[bf][l]); aSrc[l] += 64; }
    #pragma unroll
    for (int l = 0; l < 4; l++){ gl_lds16(bSrc[l], bDst[bf][l]); bSrc[l] += 64; }
  };

  stageTo(IC<0>{});                          // prologue: tile 0 in flight

  auto tile_step = [&](auto BUF, int t){
    constexpr int CB = decltype(BUF)::v;
    if (t + 1 < NT){
      stageTo(IC<CB ^ 1>{});
      asm volatile("s_waitcnt vmcnt(8)" ::: "memory");   // stage(t) landed
    } else {
      asm volatile("s_waitcnt vmcnt(0)" ::: "memory");
    }
    __builtin_amdgcn_s_barrier();            // buf[CB] visible to all waves

    bf16x8 bfr[4][2];
    #pragma unroll
    for (int p = 0; p < 4; p++){
      bf16x8 afr[2][2];
      #pragma unroll
      for (int mi = 0; mi < 2; mi++){
        afr[mi][0] = *(const bf16x8*)(fA[CB][0] + (p * 2 + mi) * 1024);
        afr[mi][1] = *(const bf16x8*)(fA[CB][1] + (p * 2 + mi) * 1024);
      }
      if (p == 0){
        #pragma unroll
        for (int nn = 0; nn < 4; nn++){
          bfr[nn][0] = *(const bf16x8*)(fB[CB][0] + nn * 1024);
          bfr[nn][1] = *(const bf16x8*)(fB[CB][1] + nn * 1024);
        }
      }
      __builtin_amdgcn_s_barrier();          // phase alignment (role-split waves)
      asm volatile("s_waitcnt lgkmcnt(0)" ::: "memory");
      __builtin_amdgcn_sched_barrier(0);
      __builtin_amdgcn_s_setprio(1);
      #pragma unroll
      for (int mi = 0; mi < 2; mi++)
        #pragma unroll
        for (int nn = 0; nn < 4; nn++)
          #pragma unroll
          for (int kk = 0; kk < 2; kk++)
            acc[p * 2 + mi][nn] = __builtin_amdgcn_mfma_f32_16x16x32_bf16(
                afr[mi][kk], bfr[nn][kk], acc[p * 2 + mi][nn], 0, 0, 0);
      __builtin_amdgcn_s_setprio(0);
      __builtin_amdgcn_s_barrier();
    }
  };

  for (int t = 0; t < NT; t += 2){           // NT even (K%128==0)
    tile_step(IC<0>{}, t);
    tile_step(IC<1>{}, t + 1);
  }

  // ---- epilogue
  float* outF = (float*)outp;
  unsigned short* outB = (unsigned short*)outp;
  #pragma unroll
  for (int mm = 0; mm < 8; mm++){
    int rowb = m0 + wm * 128 + mm * 16 + hi * 4;
    #pragma unroll
    for (int nn = 0; nn < 4; nn++){
      int col = n0 + wn * 64 + nn * 16 + la;
      float bv = BIAS ? bias[col] : 0.0f;
      #pragma unroll
      for (int r = 0; r < 4; r++){
        float val = acc[mm][nn][r] + bv;
        if (GELU_) val = gelu_f(val);
        size_t o = (size_t)(rowb + r) * N + col;
        if (OUTF32) outF[o] = val;
        else        outB[o] = f2b(val);
      }
    }
  }
}

// ---------------- GEMM BMx128 (r8 dbuf, counted vmcnt, hoisted) for N=768 ---------
template<int BM, bool BIAS, bool GELU_, bool RES, bool OUTF32>
__global__ __launch_bounds__(256, BM == 64 ? 3 : 2)
void gemm_db(const unsigned short* __restrict__ A, const unsigned short* __restrict__ Bt,
             const float* __restrict__ bias, const float* __restrict__ res,
             void* __restrict__ outp, int M, int N, int K)
{
  constexpr int MI = BM / 32;             // m-frags per wave
  constexpr int AL = (BM * 8) / 256;      // A-stage instrs per wave
  constexpr int BUFSZ = (BM + 128) * 64;  // shorts per buffer
  __shared__ unsigned short sm[2][BUFSZ];

  int tid = threadIdx.x, wid = tid >> 6, lane = tid & 63;
  int la = lane & 15, hi = lane >> 4;
  int wm = wid >> 1, wn = wid & 1;        // 2x2 waves
  int tiles_n = N >> 7;
  int bid = blockIdx.x;
  bid = (bid & 7) * (gridDim.x >> 3) + (bid >> 3);   // XCD-aware swizzle
  int m0 = (bid / tiles_n) * BM, n0 = (bid % tiles_n) << 7;
  int NT = K >> 6;

  f32x4 acc[MI][4] = {};

  const unsigned short* aSrc[AL];
  const unsigned short* bSrc[4];
  unsigned short* aDst[2][AL];
  unsigned short* bDst[2][4];
  #pragma unroll
  for (int l = 0; l < AL; l++){
    int cb = wid * (BM * 2) + l * 64;
    int idx = cb + lane;
    int row = idx >> 3, sl2 = (idx & 7) ^ (row & 7);
    aSrc[l] = A + (size_t)(m0 + row) * K + sl2 * 8;
    aDst[0][l] = &sm[0][cb * 8];
    aDst[1][l] = &sm[1][cb * 8];
  }
  #pragma unroll
  for (int l = 0; l < 4; l++){
    int cb = wid * 256 + l * 64;
    int idx = cb + lane;
    int row = idx >> 3, sl2 = (idx & 7) ^ (row & 7);
    bSrc[l] = Bt + (size_t)(n0 + row) * K + sl2 * 8;
    bDst[0][l] = &sm[0][BM * 64 + cb * 8];
    bDst[1][l] = &sm[1][BM * 64 + cb * 8];
  }

  const unsigned short* fa[2][2];
  const unsigned short* fb[2][2];
  #pragma unroll
  for (int bf = 0; bf < 2; bf++)
    #pragma unroll
    for (int kk = 0; kk < 2; kk++){
      int sw = (((kk * 4 + hi) ^ (la & 7))) * 8;
      fa[bf][kk] = &sm[bf][(wm * (BM / 2) + la) * 64 + sw];
      fb[bf][kk] = &sm[bf][BM * 64 + (wn * 64 + la) * 64 + sw];
    }

  auto stageTo = [&](auto BF){
    constexpr int bf = decltype(BF)::v;
    #pragma unroll
    for (int l = 0; l < AL; l++){ gl_lds16(aSrc[l], aDst[bf][l]); aSrc[l] += 64; }
    #pragma unroll
    for (int l = 0; l < 4; l++){ gl_lds16(bSrc[l], bDst[bf][l]); bSrc[l] += 64; }
  };

  stageTo(IC<0>{});

  auto tile_step = [&](auto BUF, int t){
    constexpr int CB = decltype(BUF)::v;
    if (t + 1 < NT){
      stageTo(IC<CB ^ 1>{});
      if constexpr (BM == 128) asm volatile("s_waitcnt vmcnt(8)" ::: "memory");
      else                     asm volatile("s_waitcnt vmcnt(6)" ::: "memory");
    } else {
      asm volatile("s_waitcnt vmcnt(0)" ::: "memory");
    }
    __builtin_amdgcn_s_barrier();

    bf16x8 afr[MI][2], bfr[4][2];
    #pragma unroll
    for (int mm = 0; mm < MI; mm++){
      afr[mm][0] = *(const bf16x8*)(fa[CB][0] + mm * 1024);
      afr[mm][1] = *(const bf16x8*)(fa[CB][1] + mm * 1024);
    }
    #pragma unroll
    for (int nn = 0; nn < 4; nn++){
      bfr[nn][0] = *(const bf16x8*)(fb[CB][0] + nn * 1024);
      bfr[nn][1] = *(const bf16x8*)(fb[CB][1] + nn * 1024);
    }
    __builtin_amdgcn_s_setprio(1);
    #pragma unroll
    for (int mm = 0; mm < MI; mm++)
      #pragma unroll
      for (int nn = 0; nn < 4; nn++)
        #pragma unroll
        for (int kk = 0; kk < 2; kk++)
          acc[mm][nn] = __builtin_amdgcn_mfma_f32_16x16x32_bf16(
              afr[mm][kk], bfr[nn][kk], acc[mm][nn], 0, 0, 0);
    __builtin_amdgcn_s_setprio(0);

    __builtin_amdgcn_s_barrier();
  };

  for (int t = 0; t < NT; t += 2){
    tile_step(IC<0>{}, t);
    tile_step(IC<1>{}, t + 1);
  }

  float* outF = (float*)outp;
  unsigned short* outB = (unsigned short*)outp;
  #pragma unroll
  for (int mm = 0; mm < MI; mm++){
    int rowb = m0 + wm * (BM / 2) + mm * 16 + hi * 4;
    #pragma unroll
    for (int nn = 0; nn < 4; nn++){
      int col = n0 + wn * 64 + nn * 16 + la;
      float bv = BIAS ? bias[col] : 0.0f;
      #pragma unroll
      for (int r = 0; r < 4; r++){
        float val = acc[mm][nn][r] + bv;
        if (GELU_) val = gelu_f(val);
        if (RES)   val += res[(size_t)(rowb + r) * N + col];
        size_t o = (size_t)(rowb + r) * N + col;
        if (OUTF32) outF[o] = val;
        else        outB[o] = f2b(val);
      }
    }
  }
}

// ---------------- sliding-window causal attention, W=64, D=64, MFMA tile ----------
__global__ __launch_bounds__(256)
void attn_k(const unsigned short* __restrict__ qkv, unsigned short* __restrict__ attn)
{
  __shared__ unsigned short Qs[64 * 72];       // stride 72: b128 reads at 8-way min
  __shared__ unsigned short Ks[128 * 72];
  __shared__ unsigned short Vt[64 * 136];      // V^T [d][s], stride 136
  __shared__ unsigned short Ps[4][16 * 136];   // per-wave P rows

  int tid = threadIdx.x, wid = tid >> 6, lane = tid & 63;
  int la = lane & 15, hi = lane >> 4;
  int blk = blockIdx.x;
  blk = (blk & 7) * (gridDim.x >> 3) + (blk >> 3);   // XCD swizzle (1536 % 8 == 0)
  int tile = blk & 15, hb = blk >> 4;
  int h = hb % 12, b = hb / 12;
  int t0 = tile << 6;

  const unsigned short* qbase = qkv + (size_t)(b * 1024) * 2304 + h * 64;

  // ---- stage Q: 64 rows x 8 chunks of 8 bf16
  #pragma unroll
  for (int r = 0; r < 2; r++){
    int idx = tid + r * 256;
    int row = idx >> 3, ch = idx & 7;
    uint4 v = *(const uint4*)(qbase + (size_t)(t0 + row) * 2304 + ch * 8);
    *(uint4*)&Qs[row * 72 + ch * 8] = v;
  }
  // ---- stage K: 128 rows (clamped at s_global<0; masked later)
  #pragma unroll
  for (int r = 0; r < 4; r++){
    int idx = tid + r * 256;
    int row = idx >> 3, ch = idx & 7;
    int sg = t0 - 64 + row; sg = sg < 0 ? 0 : sg;
    uint4 v = *(const uint4*)(qbase + 768 + (size_t)sg * 2304 + ch * 8);
    *(uint4*)&Ks[row * 72 + ch * 8] = v;
  }
  // ---- stage V transposed (s-major lane assignment -> 2-way LDS writes)
  #pragma unroll
  for (int r = 0; r < 4; r++){
    int idx = tid + r * 256;
    int s = idx & 127, ch = idx >> 7;
    int sg = t0 - 64 + s; sg = sg < 0 ? 0 : sg;
    uint4 v = *(const uint4*)(qbase + 1536 + (size_t)sg * 2304 + ch * 8);
    unsigned short tmp[8];
    *(uint4*)tmp = v;
    #pragma unroll
    for (int j = 0; j < 8; j++)
      Vt[(ch * 8 + j) * 136 + s] = tmp[j];
  }
  __syncthreads();

  // ---- S = Q K^T for 16 own rows x 128 cols (8 col-fragments x 2 k-steps)
  f32x4 sc[8];
  #pragma unroll
  for (int sj = 0; sj < 8; sj++) sc[sj] = (f32x4){0.f, 0.f, 0.f, 0.f};
  #pragma unroll
  for (int kk = 0; kk < 2; kk++){
    bf16x8 aq = *(const bf16x8*)&Qs[(wid * 16 + la) * 72 + kk * 32 + hi * 8];
    #pragma unroll
    for (int sj = 0; sj < 8; sj++){
      bf16x8 bk = *(const bf16x8*)&Ks[(sj * 16 + la) * 72 + kk * 32 + hi * 8];
      sc[sj] = __builtin_amdgcn_mfma_f32_16x16x32_bf16(aq, bk, sc[sj], 0, 0, 0);
    }
  }

  // ---- masked in-register softmax (row = wid*16 + hi*4 + r2, col = sj*16 + la)
  float inv[4];
  #pragma unroll
  for (int r2 = 0; r2 < 4; r2++){
    int row = wid * 16 + hi * 4 + r2;
    float mx = -1e30f;
    #pragma unroll
    for (int sj = 0; sj < 8; sj++){
      int sl = sj * 16 + la;
      bool valid = (sl >= row + 1) && (sl <= row + 64) && (t0 - 64 + sl >= 0);
      float sv = valid ? sc[sj][r2] * 0.125f : -1e30f;
      sc[sj][r2] = sv;
      mx = fmaxf(mx, sv);
    }
    #pragma unroll
    for (int o = 8; o >= 1; o >>= 1) mx = fmaxf(mx, __shfl_xor(mx, o));
    float sum = 0.0f;
    #pragma unroll
    for (int sj = 0; sj < 8; sj++){
      float p = __expf(sc[sj][r2] - mx);
      sc[sj][r2] = p;
      sum += p;
    }
    #pragma unroll
    for (int o = 8; o >= 1; o >>= 1) sum += __shfl_xor(sum, o);
    inv[r2] = 1.0f / sum;
  }

  // ---- P -> LDS (bf16), per-wave region
  unsigned short* myP = Ps[wid];
  #pragma unroll
  for (int sj = 0; sj < 8; sj++)
    #pragma unroll
    for (int r2 = 0; r2 < 4; r2++)
      myP[(hi * 4 + r2) * 136 + sj * 16 + la] = f2b(sc[sj][r2]);

  __syncthreads();

  // ---- O = P V  (A = P[16x128], B^T = Vt[64x128], 4 n-frags x 4 k-steps)
  f32x4 oacc[4];
  #pragma unroll
  for (int nj = 0; nj < 4; nj++) oacc[nj] = (f32x4){0.f, 0.f, 0.f, 0.f};
  #pragma unroll
  for (int ks = 0; ks < 4; ks++){
    bf16x8 ap = *(const bf16x8*)&myP[la * 136 + ks * 32 + hi * 8];
    #pragma unroll
    for (int nj = 0; nj < 4; nj++){
      bf16x8 bv = *(const bf16x8*)&Vt[(nj * 16 + la) * 136 + ks * 32 + hi * 8];
      oacc[nj] = __builtin_amdgcn_mfma_f32_16x16x32_bf16(ap, bv, oacc[nj], 0, 0, 0);
    }
  }

  // ---- write O (bf16, head-concat layout), scaled by 1/rowsum
  unsigned short* obase = attn + (size_t)(b * 1024 + t0) * 768 + h * 64;
  #pragma unroll
  for (int nj = 0; nj < 4; nj++)
    #pragma unroll
    for (int r2 = 0; r2 < 4; r2++){
      int row = wid * 16 + hi * 4 + r2;
      obase[(size_t)row * 768 + nj * 16 + la] = f2b(oacc[nj][r2] * inv[r2]);
    }
}

__global__ void aux_k(float* p){ if (threadIdx.x == 0) p[0] = 0.0f; }

// ----------------------------------------------------------------------------------
extern "C" void kernel_launch(void* const* d_in, const int* in_sizes, int n_in,
                              void* d_out, int out_size, void* d_ws, size_t ws_size,
                              hipStream_t stream)
{
  const float* x      = (const float*)d_in[0];
  const float* w_q    = (const float*)d_in[1];
  const float* w_k    = (const float*)d_in[2];
  const float* w_v    = (const float*)d_in[3];
  const float* w_proj = (const float*)d_in[4];
  const float* b_proj = (const float*)d_in[5];
  const float* w_ff1  = (const float*)d_in[6];
  const float* b_ff1  = (const float*)d_in[7];
  const float* w_ff2  = (const float*)d_in[8];
  const float* b_ff2  = (const float*)d_in[9];
  const float* g1     = (const float*)d_in[10];
  const float* g2     = (const float*)d_in[11];
  float* out = (float*)d_out;

  char* ws = (char*)d_ws;
  size_t off = 0;
  auto alloc = [&](size_t bytes){ size_t r = off; off += (bytes + 255) & ~(size_t)255; return r; };
  const size_t BT = 8 * 1024;  // 8192 rows

  unsigned short* h     = (unsigned short*)(ws + alloc(BT * 768 * 2));   // reused for attn out
  unsigned short* qkv   = (unsigned short*)(ws + alloc(BT * 3072 * 2));  // reused for ffa
  float*          x2    = (float*)         (ws + alloc(BT * 768 * 4));
  unsigned short* h2    = (unsigned short*)(ws + alloc(BT * 768 * 2));
  unsigned short* WqkvT = (unsigned short*)(ws + alloc(2304 * 768 * 2));
  unsigned short* WprojT= (unsigned short*)(ws + alloc(768 * 768 * 2));
  unsigned short* Wff1T = (unsigned short*)(ws + alloc(3072 * 768 * 2));
  unsigned short* Wff2T = (unsigned short*)(ws + alloc(768 * 3072 * 2));
  unsigned short* attn  = h;     // h dead after QKV GEMM
  unsigned short* ffa   = qkv;   // qkv dead after attention

  // weights -> bf16, transposed to [N][K]
  transpose_f2b<<<576, 256, 0, stream>>>(w_q,    WqkvT,             768, 768);
  transpose_f2b<<<576, 256, 0, stream>>>(w_k,    WqkvT + 768 * 768, 768, 768);
  transpose_f2b<<<576, 256, 0, stream>>>(w_v,    WqkvT + 1536 * 768,768, 768);
  transpose_f2b<<<576, 256, 0, stream>>>(w_proj, WprojT,            768, 768);
  transpose_f2b<<<24 * 96, 256, 0, stream>>>(w_ff1, Wff1T, 768, 3072);
  transpose_f2b<<<96 * 24, 256, 0, stream>>>(w_ff2, Wff2T, 3072, 768);

  // h = rmsnorm(x, g1)
  rmsnorm_k<<<2048, 256, 0, stream>>>(x, g1, h);

  // qkv = h @ [Wq|Wk|Wv]   (M=8192, N=2304, K=768), bf16 out — 256x256 8-wave
  gemm256<false,false,false><<<32 * 9, 512, 0, stream>>>(h, WqkvT, nullptr, qkv, 8192, 2304, 768);

  // sliding-window attention -> attn (bf16, [B*T][768] head-concat layout)
  attn_k<<<8 * 12 * 16, 256, 0, stream>>>(qkv, attn);

  // x2 = x + attn @ Wproj + b_proj   (fp32 out), BM=64 -> grid 768 (3 blocks/CU)
  gemm_db<64,true,false,true,true><<<128 * 6, 256, 0, stream>>>(attn, WprojT, b_proj, x, x2, 8192, 768, 768);

  // h2 = rmsnorm(x2, g2)
  rmsnorm_k<<<2048, 256, 0, stream>>>(x2, g2, h2);

  // ffa = gelu(h2 @ Wff1 + b_ff1)   (bf16 out, M=8192, N=3072, K=768) — 256x256
  gemm256<true,true,false><<<32 * 12, 512, 0, stream>>>(h2, Wff1T, b_ff1, ffa, 8192, 3072, 768);

  // out = x2 + ffa @ Wff2 + b_ff2   (fp32, M=8192, N=768, K=3072), BM=64
  gemm_db<64,true,false,true,true><<<128 * 6, 256, 0, stream>>>(ffa, Wff2T, b_ff2, x2, out, 8192, 768, 3072);

  // aux scalar
  aux_k<<<1, 64, 0, stream>>>(out + 6291456);
}

// Round 10
// 212.368 us; speedup vs baseline: 1.1603x; 1.1603x over previous
//
#include <hip/hip_runtime.h>
#include <cstdint>

#define DEVI __device__ __forceinline__

typedef __bf16 bf16x8 __attribute__((ext_vector_type(8)));
typedef float  f32x4  __attribute__((ext_vector_type(4)));

template<int V> struct IC { static constexpr int v = V; };

DEVI unsigned short f2b(float f){
  unsigned u = __builtin_bit_cast(unsigned, f);
  unsigned r = u + 0x7FFF + ((u >> 16) & 1);
  return (unsigned short)(r >> 16);
}
DEVI float b2f(unsigned short s){
  unsigned u = ((unsigned)s) << 16;
  return __builtin_bit_cast(float, u);
}
DEVI float gelu_f(float x){
  float u = 0.7978845608028654f * (x + 0.044715f * x * x * x);
  float e = __expf(2.0f * u);
  return x * (1.0f - 1.0f / (e + 1.0f));   // == 0.5x(1+tanh(u)), safe at e->inf / e->0
}
DEVI void gl_lds16(const unsigned short* g, unsigned short* l){
  __builtin_amdgcn_global_load_lds(
      (const __attribute__((address_space(1))) unsigned int*)g,
      (__attribute__((address_space(3))) unsigned int*)l, 16, 0, 0);
}

// ---------------- fused weight transpose + f32->bf16 (ONE launch for all 6) -------
// in[R][C] f32 -> out[C][R] bf16, 32x32 tiles, 256 threads.
// Ranges: [0,576) w_q | [576,1152) w_k | [1152,1728) w_v | [1728,2304) w_proj
//         [2304,4608) w_ff1 (768x3072) | [4608,6912) w_ff2 (3072x768)
__global__ __launch_bounds__(256)
void transpose_all(const float* __restrict__ w_q, const float* __restrict__ w_k,
                   const float* __restrict__ w_v, const float* __restrict__ w_proj,
                   const float* __restrict__ w_ff1, const float* __restrict__ w_ff2,
                   unsigned short* __restrict__ WqkvT, unsigned short* __restrict__ WprojT,
                   unsigned short* __restrict__ Wff1T, unsigned short* __restrict__ Wff2T)
{
  __shared__ float tile[32][33];
  int blk = blockIdx.x;
  const float* in; unsigned short* out; int R, C, b0;
  if      (blk < 576) { in = w_q;    out = WqkvT;              R = 768;  C = 768;  b0 = 0;    }
  else if (blk < 1152){ in = w_k;    out = WqkvT + 768 * 768;  R = 768;  C = 768;  b0 = 576;  }
  else if (blk < 1728){ in = w_v;    out = WqkvT + 1536 * 768; R = 768;  C = 768;  b0 = 1152; }
  else if (blk < 2304){ in = w_proj; out = WprojT;             R = 768;  C = 768;  b0 = 1728; }
  else if (blk < 4608){ in = w_ff1;  out = Wff1T;              R = 768;  C = 3072; b0 = 2304; }
  else                { in = w_ff2;  out = Wff2T;              R = 3072; C = 768;  b0 = 4608; }
  int lb = blk - b0;
  int nbx = C >> 5;
  int bx = lb % nbx, by = lb / nbx;
  int c0 = bx << 5, r0 = by << 5;
  int tx = threadIdx.x & 31, ty = threadIdx.x >> 5;   // 32 x 8
  #pragma unroll
  for (int j = 0; j < 32; j += 8)
    tile[ty + j][tx] = in[(size_t)(r0 + ty + j) * C + c0 + tx];
  __syncthreads();
  #pragma unroll
  for (int j = 0; j < 32; j += 8)
    out[(size_t)(c0 + ty + j) * R + r0 + tx] = f2b(tile[tx][ty + j]);
}

// ---------------- RMSNorm: x f32 [rows][768] -> out bf16, 1 wave per row ----------
__global__ __launch_bounds__(256)
void rmsnorm_k(const float* __restrict__ x, const float* __restrict__ g,
               unsigned short* __restrict__ out)
{
  int wid = threadIdx.x >> 6, lane = threadIdx.x & 63;
  size_t row = (size_t)blockIdx.x * 4 + wid;
  const float* xr = x + row * 768;
  float4 v[3];
  float ss = 0.0f;
  #pragma unroll
  for (int c = 0; c < 3; c++){
    v[c] = *(const float4*)&xr[lane * 4 + c * 256];
    ss += v[c].x * v[c].x + v[c].y * v[c].y + v[c].z * v[c].z + v[c].w * v[c].w;
  }
  #pragma unroll
  for (int o = 32; o >= 1; o >>= 1) ss += __shfl_xor(ss, o);
  float rs = rsqrtf(ss * (1.0f / 768.0f) + 1e-6f);
  #pragma unroll
  for (int c = 0; c < 3; c++){
    const float4 gv = *(const float4*)&g[lane * 4 + c * 256];
    ushort4 o4;
    o4.x = f2b(v[c].x * rs * gv.x);
    o4.y = f2b(v[c].y * rs * gv.y);
    o4.z = f2b(v[c].z * rs * gv.z);
    o4.w = f2b(v[c].w * rs * gv.w);
    *(ushort4*)&out[row * 768 + lane * 4 + c * 256] = o4;
  }
}

// ---------------- GEMM 64x128, BK=64, dbuf, counted vmcnt, hoisted addressing -----
// r8 structure, BM=64 everywhere: 48KB LDS -> 3 blocks/CU (12 waves) — measured
// ~820 TF on proj/FF2 vs 510-670 at BM=128 (occupancy beats frag density here).
// All grids are EXACT multiples of 768 block-slots (3/CU x 256 CU): no tails.
// Requires M%64==0, N%128==0, K%128==0, grid%8==0.
template<bool BIAS, bool GELU_, bool RES, bool OUTF32>
__global__ __launch_bounds__(256, 3)
void gemm_db(const unsigned short* __restrict__ A, const unsigned short* __restrict__ Bt,
             const float* __restrict__ bias, const float* __restrict__ res,
             void* __restrict__ outp, int M, int N, int K)
{
  constexpr int BM = 64;
  constexpr int MI = 2;                   // m-frags per wave
  constexpr int AL = 2;                   // A-stage instrs per wave
  constexpr int BUFSZ = (BM + 128) * 64;  // shorts per buffer
  __shared__ unsigned short sm[2][BUFSZ];

  int tid = threadIdx.x, wid = tid >> 6, lane = tid & 63;
  int la = lane & 15, hi = lane >> 4;
  int wm = wid >> 1, wn = wid & 1;        // 2x2 waves
  int tiles_n = N >> 7;
  int bid = blockIdx.x;
  bid = (bid & 7) * (gridDim.x >> 3) + (bid >> 3);   // XCD-aware swizzle
  int m0 = (bid / tiles_n) * BM, n0 = (bid % tiles_n) << 7;
  int NT = K >> 6;

  f32x4 acc[MI][4] = {};

  const unsigned short* aSrc[AL];
  const unsigned short* bSrc[4];
  unsigned short* aDst[2][AL];
  unsigned short* bDst[2][4];
  #pragma unroll
  for (int l = 0; l < AL; l++){
    int cb = wid * (BM * 2) + l * 64;
    int idx = cb + lane;
    int row = idx >> 3, sl2 = (idx & 7) ^ (row & 7);
    aSrc[l] = A + (size_t)(m0 + row) * K + sl2 * 8;
    aDst[0][l] = &sm[0][cb * 8];
    aDst[1][l] = &sm[1][cb * 8];
  }
  #pragma unroll
  for (int l = 0; l < 4; l++){
    int cb = wid * 256 + l * 64;
    int idx = cb + lane;
    int row = idx >> 3, sl2 = (idx & 7) ^ (row & 7);
    bSrc[l] = Bt + (size_t)(n0 + row) * K + sl2 * 8;
    bDst[0][l] = &sm[0][BM * 64 + cb * 8];
    bDst[1][l] = &sm[1][BM * 64 + cb * 8];
  }

  const unsigned short* fa[2][2];
  const unsigned short* fb[2][2];
  #pragma unroll
  for (int bf = 0; bf < 2; bf++)
    #pragma unroll
    for (int kk = 0; kk < 2; kk++){
      int sw = (((kk * 4 + hi) ^ (la & 7))) * 8;
      fa[bf][kk] = &sm[bf][(wm * (BM / 2) + la) * 64 + sw];
      fb[bf][kk] = &sm[bf][BM * 64 + (wn * 64 + la) * 64 + sw];
    }

  auto stageTo = [&](auto BF){
    constexpr int bf = decltype(BF)::v;
    #pragma unroll
    for (int l = 0; l < AL; l++){ gl_lds16(aSrc[l], aDst[bf][l]); aSrc[l] += 64; }
    #pragma unroll
    for (int l = 0; l < 4; l++){ gl_lds16(bSrc[l], bDst[bf][l]); bSrc[l] += 64; }
  };

  stageTo(IC<0>{});

  auto tile_step = [&](auto BUF, int t){
    constexpr int CB = decltype(BUF)::v;
    if (t + 1 < NT){
      stageTo(IC<CB ^ 1>{});
      asm volatile("s_waitcnt vmcnt(6)" ::: "memory");   // stage(t) landed
    } else {
      asm volatile("s_waitcnt vmcnt(0)" ::: "memory");
    }
    __builtin_amdgcn_s_barrier();

    bf16x8 afr[MI][2], bfr[4][2];
    #pragma unroll
    for (int mm = 0; mm < MI; mm++){
      afr[mm][0] = *(const bf16x8*)(fa[CB][0] + mm * 1024);
      afr[mm][1] = *(const bf16x8*)(fa[CB][1] + mm * 1024);
    }
    #pragma unroll
    for (int nn = 0; nn < 4; nn++){
      bfr[nn][0] = *(const bf16x8*)(fb[CB][0] + nn * 1024);
      bfr[nn][1] = *(const bf16x8*)(fb[CB][1] + nn * 1024);
    }
    __builtin_amdgcn_s_setprio(1);
    #pragma unroll
    for (int mm = 0; mm < MI; mm++)
      #pragma unroll
      for (int nn = 0; nn < 4; nn++)
        #pragma unroll
        for (int kk = 0; kk < 2; kk++)
          acc[mm][nn] = __builtin_amdgcn_mfma_f32_16x16x32_bf16(
              afr[mm][kk], bfr[nn][kk], acc[mm][nn], 0, 0, 0);
    __builtin_amdgcn_s_setprio(0);

    __builtin_amdgcn_s_barrier();
  };

  for (int t = 0; t < NT; t += 2){                     // NT even (K%128==0)
    tile_step(IC<0>{}, t);
    tile_step(IC<1>{}, t + 1);
  }

  float* outF = (float*)outp;
  unsigned short* outB = (unsigned short*)outp;
  #pragma unroll
  for (int mm = 0; mm < MI; mm++){
    int rowb = m0 + wm * (BM / 2) + mm * 16 + hi * 4;
    #pragma unroll
    for (int nn = 0; nn < 4; nn++){
      int col = n0 + wn * 64 + nn * 16 + la;
      float bv = BIAS ? bias[col] : 0.0f;
      #pragma unroll
      for (int r = 0; r < 4; r++){
        float val = acc[mm][nn][r] + bv;
        if (GELU_) val = gelu_f(val);
        if (RES)   val += res[(size_t)(rowb + r) * N + col];
        size_t o = (size_t)(rowb + r) * N + col;
        if (OUTF32) outF[o] = val;
        else        outB[o] = f2b(val);
      }
    }
  }
}

// ---------------- sliding-window causal attention, W=64, D=64, MFMA tile ----------
__global__ __launch_bounds__(256)
void attn_k(const unsigned short* __restrict__ qkv, unsigned short* __restrict__ attn)
{
  __shared__ unsigned short Qs[64 * 72];       // stride 72: b128 reads at 8-way min
  __shared__ unsigned short Ks[128 * 72];
  __shared__ unsigned short Vt[64 * 136];      // V^T [d][s], stride 136
  __shared__ unsigned short Ps[4][16 * 136];   // per-wave P rows

  int tid = threadIdx.x, wid = tid >> 6, lane = tid & 63;
  int la = lane & 15, hi = lane >> 4;
  int blk = blockIdx.x;
  blk = (blk & 7) * (gridDim.x >> 3) + (blk >> 3);   // XCD swizzle (1536 % 8 == 0)
  int tile = blk & 15, hb = blk >> 4;
  int h = hb % 12, b = hb / 12;
  int t0 = tile << 6;

  const unsigned short* qbase = qkv + (size_t)(b * 1024) * 2304 + h * 64;

  // ---- stage Q: 64 rows x 8 chunks of 8 bf16
  #pragma unroll
  for (int r = 0; r < 2; r++){
    int idx = tid + r * 256;
    int row = idx >> 3, ch = idx & 7;
    uint4 v = *(const uint4*)(qbase + (size_t)(t0 + row) * 2304 + ch * 8);
    *(uint4*)&Qs[row * 72 + ch * 8] = v;
  }
  // ---- stage K: 128 rows (clamped at s_global<0; masked later)
  #pragma unroll
  for (int r = 0; r < 4; r++){
    int idx = tid + r * 256;
    int row = idx >> 3, ch = idx & 7;
    int sg = t0 - 64 + row; sg = sg < 0 ? 0 : sg;
    uint4 v = *(const uint4*)(qbase + 768 + (size_t)sg * 2304 + ch * 8);
    *(uint4*)&Ks[row * 72 + ch * 8] = v;
  }
  // ---- stage V transposed (s-major lane assignment -> 2-way LDS writes)
  #pragma unroll
  for (int r = 0; r < 4; r++){
    int idx = tid + r * 256;
    int s = idx & 127, ch = idx >> 7;
    int sg = t0 - 64 + s; sg = sg < 0 ? 0 : sg;
    uint4 v = *(const uint4*)(qbase + 1536 + (size_t)sg * 2304 + ch * 8);
    unsigned short tmp[8];
    *(uint4*)tmp = v;
    #pragma unroll
    for (int j = 0; j < 8; j++)
      Vt[(ch * 8 + j) * 136 + s] = tmp[j];
  }
  __syncthreads();

  // ---- S = Q K^T for 16 own rows x 128 cols (8 col-fragments x 2 k-steps)
  f32x4 sc[8];
  #pragma unroll
  for (int sj = 0; sj < 8; sj++) sc[sj] = (f32x4){0.f, 0.f, 0.f, 0.f};
  #pragma unroll
  for (int kk = 0; kk < 2; kk++){
    bf16x8 aq = *(const bf16x8*)&Qs[(wid * 16 + la) * 72 + kk * 32 + hi * 8];
    #pragma unroll
    for (int sj = 0; sj < 8; sj++){
      bf16x8 bk = *(const bf16x8*)&Ks[(sj * 16 + la) * 72 + kk * 32 + hi * 8];
      sc[sj] = __builtin_amdgcn_mfma_f32_16x16x32_bf16(aq, bk, sc[sj], 0, 0, 0);
    }
  }

  // ---- masked in-register softmax (row = wid*16 + hi*4 + r2, col = sj*16 + la)
  float inv[4];
  #pragma unroll
  for (int r2 = 0; r2 < 4; r2++){
    int row = wid * 16 + hi * 4 + r2;
    float mx = -1e30f;
    #pragma unroll
    for (int sj = 0; sj < 8; sj++){
      int sl = sj * 16 + la;
      bool valid = (sl >= row + 1) && (sl <= row + 64) && (t0 - 64 + sl >= 0);
      float sv = valid ? sc[sj][r2] * 0.125f : -1e30f;
      sc[sj][r2] = sv;
      mx = fmaxf(mx, sv);
    }
    #pragma unroll
    for (int o = 8; o >= 1; o >>= 1) mx = fmaxf(mx, __shfl_xor(mx, o));
    float sum = 0.0f;
    #pragma unroll
    for (int sj = 0; sj < 8; sj++){
      float p = __expf(sc[sj][r2] - mx);
      sc[sj][r2] = p;
      sum += p;
    }
    #pragma unroll
    for (int o = 8; o >= 1; o >>= 1) sum += __shfl_xor(sum, o);
    inv[r2] = 1.0f / sum;
  }

  // ---- P -> LDS (bf16), per-wave region
  unsigned short* myP = Ps[wid];
  #pragma unroll
  for (int sj = 0; sj < 8; sj++)
    #pragma unroll
    for (int r2 = 0; r2 < 4; r2++)
      myP[(hi * 4 + r2) * 136 + sj * 16 + la] = f2b(sc[sj][r2]);

  __syncthreads();

  // ---- O = P V  (A = P[16x128], B^T = Vt[64x128], 4 n-frags x 4 k-steps)
  f32x4 oacc[4];
  #pragma unroll
  for (int nj = 0; nj < 4; nj++) oacc[nj] = (f32x4){0.f, 0.f, 0.f, 0.f};
  #pragma unroll
  for (int ks = 0; ks < 4; ks++){
    bf16x8 ap = *(const bf16x8*)&myP[la * 136 + ks * 32 + hi * 8];
    #pragma unroll
    for (int nj = 0; nj < 4; nj++){
      bf16x8 bv = *(const bf16x8*)&Vt[(nj * 16 + la) * 136 + ks * 32 + hi * 8];
      oacc[nj] = __builtin_amdgcn_mfma_f32_16x16x32_bf16(ap, bv, oacc[nj], 0, 0, 0);
    }
  }

  // ---- write O (bf16, head-concat layout), scaled by 1/rowsum
  unsigned short* obase = attn + (size_t)(b * 1024 + t0) * 768 + h * 64;
  #pragma unroll
  for (int nj = 0; nj < 4; nj++)
    #pragma unroll
    for (int r2 = 0; r2 < 4; r2++){
      int row = wid * 16 + hi * 4 + r2;
      obase[(size_t)row * 768 + nj * 16 + la] = f2b(oacc[nj][r2] * inv[r2]);
    }
}

__global__ void aux_k(float* p){ if (threadIdx.x == 0) p[0] = 0.0f; }

// ----------------------------------------------------------------------------------
extern "C" void kernel_launch(void* const* d_in, const int* in_sizes, int n_in,
                              void* d_out, int out_size, void* d_ws, size_t ws_size,
                              hipStream_t stream)
{
  const float* x      = (const float*)d_in[0];
  const float* w_q    = (const float*)d_in[1];
  const float* w_k    = (const float*)d_in[2];
  const float* w_v    = (const float*)d_in[3];
  const float* w_proj = (const float*)d_in[4];
  const float* b_proj = (const float*)d_in[5];
  const float* w_ff1  = (const float*)d_in[6];
  const float* b_ff1  = (const float*)d_in[7];
  const float* w_ff2  = (const float*)d_in[8];
  const float* b_ff2  = (const float*)d_in[9];
  const float* g1     = (const float*)d_in[10];
  const float* g2     = (const float*)d_in[11];
  float* out = (float*)d_out;

  char* ws = (char*)d_ws;
  size_t off = 0;
  auto alloc = [&](size_t bytes){ size_t r = off; off += (bytes + 255) & ~(size_t)255; return r; };
  const size_t BT = 8 * 1024;  // 8192 rows

  unsigned short* h     = (unsigned short*)(ws + alloc(BT * 768 * 2));   // reused for attn out
  unsigned short* qkv   = (unsigned short*)(ws + alloc(BT * 3072 * 2));  // reused for ffa
  float*          x2    = (float*)         (ws + alloc(BT * 768 * 4));
  unsigned short* h2    = (unsigned short*)(ws + alloc(BT * 768 * 2));
  unsigned short* WqkvT = (unsigned short*)(ws + alloc(2304 * 768 * 2));
  unsigned short* WprojT= (unsigned short*)(ws + alloc(768 * 768 * 2));
  unsigned short* Wff1T = (unsigned short*)(ws + alloc(3072 * 768 * 2));
  unsigned short* Wff2T = (unsigned short*)(ws + alloc(768 * 3072 * 2));
  unsigned short* attn  = h;     // h dead after QKV GEMM
  unsigned short* ffa   = qkv;   // qkv dead after attention

  // all weights -> bf16 transposed, ONE launch
  transpose_all<<<6912, 256, 0, stream>>>(w_q, w_k, w_v, w_proj, w_ff1, w_ff2,
                                          WqkvT, WprojT, Wff1T, Wff2T);

  // h = rmsnorm(x, g1)
  rmsnorm_k<<<2048, 256, 0, stream>>>(x, g1, h);

  // qkv = h @ [Wq|Wk|Wv]   (M=8192, N=2304, K=768) — grid 2304 = 3.0 rounds @3/CU
  gemm_db<false,false,false,false><<<2304, 256, 0, stream>>>(h, WqkvT, nullptr, nullptr, qkv, 8192, 2304, 768);

  // sliding-window attention -> attn (bf16, [B*T][768] head-concat layout)
  attn_k<<<8 * 12 * 16, 256, 0, stream>>>(qkv, attn);

  // x2 = x + attn @ Wproj + b_proj   (fp32 out) — grid 768 = 1.0 round
  gemm_db<true,false,true,true><<<768, 256, 0, stream>>>(attn, WprojT, b_proj, x, x2, 8192, 768, 768);

  // h2 = rmsnorm(x2, g2)
  rmsnorm_k<<<2048, 256, 0, stream>>>(x2, g2, h2);

  // ffa = gelu(h2 @ Wff1 + b_ff1)   (M=8192, N=3072, K=768) — grid 3072 = 4.0 rounds
  gemm_db<true,true,false,false><<<3072, 256, 0, stream>>>(h2, Wff1T, b_ff1, nullptr, ffa, 8192, 3072, 768);

  // out = x2 + ffa @ Wff2 + b_ff2   (M=8192, N=768, K=3072) — grid 768 = 1.0 round
  gemm_db<true,false,true,true><<<768, 256, 0, stream>>>(ffa, Wff2T, b_ff2, x2, out, 8192, 768, 3072);

  // aux scalar
  aux_k<<<1, 64, 0, stream>>>(out + 6291456);
}

// Round 11
// 208.757 us; speedup vs baseline: 1.1804x; 1.0173x over previous
//
#include <hip/hip_runtime.h>
#include <cstdint>

#define DEVI __device__ __forceinline__

typedef __bf16 bf16x8 __attribute__((ext_vector_type(8)));
typedef float  f32x4  __attribute__((ext_vector_type(4)));

template<int V> struct IC { static constexpr int v = V; };

DEVI unsigned short f2b(float f){
  unsigned u = __builtin_bit_cast(unsigned, f);
  unsigned r = u + 0x7FFF + ((u >> 16) & 1);
  return (unsigned short)(r >> 16);
}
DEVI float b2f(unsigned short s){
  unsigned u = ((unsigned)s) << 16;
  return __builtin_bit_cast(float, u);
}
DEVI float gelu_f(float x){
  float u = 0.7978845608028654f * (x + 0.044715f * x * x * x);
  float e = __expf(2.0f * u);
  return x * (1.0f - 1.0f / (e + 1.0f));   // == 0.5x(1+tanh(u)), safe at e->inf / e->0
}
DEVI void gl_lds16(const unsigned short* g, unsigned short* l){
  __builtin_amdgcn_global_load_lds(
      (const __attribute__((address_space(1))) unsigned int*)g,
      (__attribute__((address_space(3))) unsigned int*)l, 16, 0, 0);
}

// ---------------- fused weight transpose + f32->bf16 (ONE launch for all 6) -------
__global__ __launch_bounds__(256)
void transpose_all(const float* __restrict__ w_q, const float* __restrict__ w_k,
                   const float* __restrict__ w_v, const float* __restrict__ w_proj,
                   const float* __restrict__ w_ff1, const float* __restrict__ w_ff2,
                   unsigned short* __restrict__ WqkvT, unsigned short* __restrict__ WprojT,
                   unsigned short* __restrict__ Wff1T, unsigned short* __restrict__ Wff2T)
{
  __shared__ float tile[32][33];
  int blk = blockIdx.x;
  const float* in; unsigned short* out; int R, C, b0;
  if      (blk < 576) { in = w_q;    out = WqkvT;              R = 768;  C = 768;  b0 = 0;    }
  else if (blk < 1152){ in = w_k;    out = WqkvT + 768 * 768;  R = 768;  C = 768;  b0 = 576;  }
  else if (blk < 1728){ in = w_v;    out = WqkvT + 1536 * 768; R = 768;  C = 768;  b0 = 1152; }
  else if (blk < 2304){ in = w_proj; out = WprojT;             R = 768;  C = 768;  b0 = 1728; }
  else if (blk < 4608){ in = w_ff1;  out = Wff1T;              R = 768;  C = 3072; b0 = 2304; }
  else                { in = w_ff2;  out = Wff2T;              R = 3072; C = 768;  b0 = 4608; }
  int lb = blk - b0;
  int nbx = C >> 5;
  int bx = lb % nbx, by = lb / nbx;
  int c0 = bx << 5, r0 = by << 5;
  int tx = threadIdx.x & 31, ty = threadIdx.x >> 5;   // 32 x 8
  #pragma unroll
  for (int j = 0; j < 32; j += 8)
    tile[ty + j][tx] = in[(size_t)(r0 + ty + j) * C + c0 + tx];
  __syncthreads();
  #pragma unroll
  for (int j = 0; j < 32; j += 8)
    out[(size_t)(c0 + ty + j) * R + r0 + tx] = f2b(tile[tx][ty + j]);
}

// ---------------- RMSNorm: x f32 [rows][768] -> out bf16, 1 wave per row ----------
__global__ __launch_bounds__(256)
void rmsnorm_k(const float* __restrict__ x, const float* __restrict__ g,
               unsigned short* __restrict__ out)
{
  int wid = threadIdx.x >> 6, lane = threadIdx.x & 63;
  size_t row = (size_t)blockIdx.x * 4 + wid;
  const float* xr = x + row * 768;
  float4 v[3];
  float ss = 0.0f;
  #pragma unroll
  for (int c = 0; c < 3; c++){
    v[c] = *(const float4*)&xr[lane * 4 + c * 256];
    ss += v[c].x * v[c].x + v[c].y * v[c].y + v[c].z * v[c].z + v[c].w * v[c].w;
  }
  #pragma unroll
  for (int o = 32; o >= 1; o >>= 1) ss += __shfl_xor(ss, o);
  float rs = rsqrtf(ss * (1.0f / 768.0f) + 1e-6f);
  #pragma unroll
  for (int c = 0; c < 3; c++){
    const float4 gv = *(const float4*)&g[lane * 4 + c * 256];
    ushort4 o4;
    o4.x = f2b(v[c].x * rs * gv.x);
    o4.y = f2b(v[c].y * rs * gv.y);
    o4.z = f2b(v[c].z * rs * gv.z);
    o4.w = f2b(v[c].w * rs * gv.w);
    *(ushort4*)&out[row * 768 + lane * 4 + c * 256] = o4;
  }
}

// ---------------- GEMM 64x128 PERSISTENT: TPB output tiles per block --------------
// r10 structure (BM=64, BK=64, dbuf, counted vmcnt(6), XOR swizzle, hoisted addr),
// plus: grid is ALWAYS 768 (3 blocks/CU x 256 CU, one exact round); each block
// processes TPB consecutive output tiles as ONE continuous pipeline: during the
// last K-step of tile i the first K-tile of tile i+1 is staged (src pointers reset
// via per-lane constant offsets), so the HBM-latency prologue is paid once per
// block instead of once per output tile (FF1: 4x fewer cold starts).
// Dbuf parity continues across tiles (NT even). Epilogue stores overlap the
// in-flight prefetch; they inflate vmcnt so the next vmcnt(6) is strictly MORE
// conservative — safe. Requires M%64==0, N%128==0, K%128==0, grid*TPB == tiles.
template<int TPB, bool BIAS, bool GELU_, bool RES, bool OUTF32>
__global__ __launch_bounds__(256, 3)
void gemm_db(const unsigned short* __restrict__ A, const unsigned short* __restrict__ Bt,
             const float* __restrict__ bias, const float* __restrict__ res,
             void* __restrict__ outp, int M, int N, int K)
{
  constexpr int BM = 64;
  constexpr int MI = 2;                   // m-frags per wave
  constexpr int AL = 2;                   // A-stage instrs per wave
  constexpr int BUFSZ = (BM + 128) * 64;  // shorts per buffer
  __shared__ unsigned short sm[2][BUFSZ];

  int tid = threadIdx.x, wid = tid >> 6, lane = tid & 63;
  int la = lane & 15, hi = lane >> 4;
  int wm = wid >> 1, wn = wid & 1;        // 2x2 waves
  int tiles_n = N >> 7;
  int bid = blockIdx.x;
  bid = (bid & 7) * (gridDim.x >> 3) + (bid >> 3);   // XCD-aware swizzle
  int g0 = bid * TPB;                     // first output tile (consecutive: A reuse)
  int NT = K >> 6;

  // ---- per-lane constant address components (tile-independent)
  size_t constA[AL]; unsigned short* aDst[2][AL];
  size_t constB[4];  unsigned short* bDst[2][4];
  #pragma unroll
  for (int l = 0; l < AL; l++){
    int cb = wid * (BM * 2) + l * 64;
    int idx = cb + lane;
    int row = idx >> 3, sl2 = (idx & 7) ^ (row & 7);
    constA[l] = (size_t)row * K + sl2 * 8;
    aDst[0][l] = &sm[0][cb * 8];
    aDst[1][l] = &sm[1][cb * 8];
  }
  #pragma unroll
  for (int l = 0; l < 4; l++){
    int cb = wid * 256 + l * 64;
    int idx = cb + lane;
    int row = idx >> 3, sl2 = (idx & 7) ^ (row & 7);
    constB[l] = (size_t)row * K + sl2 * 8;
    bDst[0][l] = &sm[0][BM * 64 + cb * 8];
    bDst[1][l] = &sm[1][BM * 64 + cb * 8];
  }

  // ---- fragment base pointers [buf][kk] (XOR lane-constant: row&7 == la&7)
  const unsigned short* fa[2][2];
  const unsigned short* fb[2][2];
  #pragma unroll
  for (int bf = 0; bf < 2; bf++)
    #pragma unroll
    for (int kk = 0; kk < 2; kk++){
      int sw = (((kk * 4 + hi) ^ (la & 7))) * 8;
      fa[bf][kk] = &sm[bf][(wm * (BM / 2) + la) * 64 + sw];
      fb[bf][kk] = &sm[bf][BM * 64 + (wn * 64 + la) * 64 + sw];
    }

  // ---- mutable stage source pointers (reset at each output-tile switch)
  const unsigned short* aSrc[AL];
  const unsigned short* bSrc[4];
  auto setSrc = [&](int g){
    int m0 = (g / tiles_n) * BM, n0 = (g % tiles_n) << 7;
    #pragma unroll
    for (int l = 0; l < AL; l++) aSrc[l] = A  + (size_t)m0 * K + constA[l];
    #pragma unroll
    for (int l = 0; l < 4;  l++) bSrc[l] = Bt + (size_t)n0 * K + constB[l];
  };
  auto stageTo = [&](auto BF){
    constexpr int bf = decltype(BF)::v;
    #pragma unroll
    for (int l = 0; l < AL; l++){ gl_lds16(aSrc[l], aDst[bf][l]); aSrc[l] += 64; }
    #pragma unroll
    for (int l = 0; l < 4; l++){ gl_lds16(bSrc[l], bDst[bf][l]); bSrc[l] += 64; }
  };

  setSrc(g0);
  stageTo(IC<0>{});                        // prologue: ONE cold start per block

  float* outF = (float*)outp;
  unsigned short* outB = (unsigned short*)outp;

  for (int ot = 0; ot < TPB; ot++){
    int g = g0 + ot;
    int m0 = (g / tiles_n) * BM, n0 = (g % tiles_n) << 7;

    f32x4 acc[MI][4] = {};

    auto tile_step = [&](auto BUF, int t){
      constexpr int CB = decltype(BUF)::v;
      if (t + 1 < NT || ot + 1 < TPB){
        if (t + 1 == NT) setSrc(g + 1);    // cross into next output tile's K=0
        stageTo(IC<CB ^ 1>{});
        asm volatile("s_waitcnt vmcnt(6)" ::: "memory");   // stage(t) landed
      } else {
        asm volatile("s_waitcnt vmcnt(0)" ::: "memory");
      }
      __builtin_amdgcn_s_barrier();

      bf16x8 afr[MI][2], bfr[4][2];
      #pragma unroll
      for (int mm = 0; mm < MI; mm++){
        afr[mm][0] = *(const bf16x8*)(fa[CB][0] + mm * 1024);
        afr[mm][1] = *(const bf16x8*)(fa[CB][1] + mm * 1024);
      }
      #pragma unroll
      for (int nn = 0; nn < 4; nn++){
        bfr[nn][0] = *(const bf16x8*)(fb[CB][0] + nn * 1024);
        bfr[nn][1] = *(const bf16x8*)(fb[CB][1] + nn * 1024);
      }
      __builtin_amdgcn_s_setprio(1);
      #pragma unroll
      for (int mm = 0; mm < MI; mm++)
        #pragma unroll
        for (int nn = 0; nn < 4; nn++)
          #pragma unroll
          for (int kk = 0; kk < 2; kk++)
            acc[mm][nn] = __builtin_amdgcn_mfma_f32_16x16x32_bf16(
                afr[mm][kk], bfr[nn][kk], acc[mm][nn], 0, 0, 0);
      __builtin_amdgcn_s_setprio(0);

      __builtin_amdgcn_s_barrier();
    };

    for (int t = 0; t < NT; t += 2){       // NT even (K%128==0)
      tile_step(IC<0>{}, t);
      tile_step(IC<1>{}, t + 1);
    }

    // ---- epilogue for tile g (overlaps next tile's in-flight kt=0 prefetch)
    #pragma unroll
    for (int mm = 0; mm < MI; mm++){
      int rowb = m0 + wm * (BM / 2) + mm * 16 + hi * 4;
      #pragma unroll
      for (int nn = 0; nn < 4; nn++){
        int col = n0 + wn * 64 + nn * 16 + la;
        float bv = BIAS ? bias[col] : 0.0f;
        #pragma unroll
        for (int r = 0; r < 4; r++){
          float val = acc[mm][nn][r] + bv;
          if (GELU_) val = gelu_f(val);
          if (RES)   val += res[(size_t)(rowb + r) * N + col];
          size_t o = (size_t)(rowb + r) * N + col;
          if (OUTF32) outF[o] = val;
          else        outB[o] = f2b(val);
        }
      }
    }
  }
}

// ---------------- sliding-window causal attention, W=64, D=64, MFMA tile ----------
__global__ __launch_bounds__(256)
void attn_k(const unsigned short* __restrict__ qkv, unsigned short* __restrict__ attn)
{
  __shared__ unsigned short Qs[64 * 72];       // stride 72: b128 reads at 8-way min
  __shared__ unsigned short Ks[128 * 72];
  __shared__ unsigned short Vt[64 * 136];      // V^T [d][s], stride 136
  __shared__ unsigned short Ps[4][16 * 136];   // per-wave P rows

  int tid = threadIdx.x, wid = tid >> 6, lane = tid & 63;
  int la = lane & 15, hi = lane >> 4;
  int blk = blockIdx.x;
  blk = (blk & 7) * (gridDim.x >> 3) + (blk >> 3);   // XCD swizzle (1536 % 8 == 0)
  int tile = blk & 15, hb = blk >> 4;
  int h = hb % 12, b = hb / 12;
  int t0 = tile << 6;

  const unsigned short* qbase = qkv + (size_t)(b * 1024) * 2304 + h * 64;

  // ---- stage Q: 64 rows x 8 chunks of 8 bf16
  #pragma unroll
  for (int r = 0; r < 2; r++){
    int idx = tid + r * 256;
    int row = idx >> 3, ch = idx & 7;
    uint4 v = *(const uint4*)(qbase + (size_t)(t0 + row) * 2304 + ch * 8);
    *(uint4*)&Qs[row * 72 + ch * 8] = v;
  }
  // ---- stage K: 128 rows (clamped at s_global<0; masked later)
  #pragma unroll
  for (int r = 0; r < 4; r++){
    int idx = tid + r * 256;
    int row = idx >> 3, ch = idx & 7;
    int sg = t0 - 64 + row; sg = sg < 0 ? 0 : sg;
    uint4 v = *(const uint4*)(qbase + 768 + (size_t)sg * 2304 + ch * 8);
    *(uint4*)&Ks[row * 72 + ch * 8] = v;
  }
  // ---- stage V transposed (s-major lane assignment -> 2-way LDS writes)
  #pragma unroll
  for (int r = 0; r < 4; r++){
    int idx = tid + r * 256;
    int s = idx & 127, ch = idx >> 7;
    int sg = t0 - 64 + s; sg = sg < 0 ? 0 : sg;
    uint4 v = *(const uint4*)(qbase + 1536 + (size_t)sg * 2304 + ch * 8);
    unsigned short tmp[8];
    *(uint4*)tmp = v;
    #pragma unroll
    for (int j = 0; j < 8; j++)
      Vt[(ch * 8 + j) * 136 + s] = tmp[j];
  }
  __syncthreads();

  // ---- S = Q K^T for 16 own rows x 128 cols (8 col-fragments x 2 k-steps)
  f32x4 sc[8];
  #pragma unroll
  for (int sj = 0; sj < 8; sj++) sc[sj] = (f32x4){0.f, 0.f, 0.f, 0.f};
  #pragma unroll
  for (int kk = 0; kk < 2; kk++){
    bf16x8 aq = *(const bf16x8*)&Qs[(wid * 16 + la) * 72 + kk * 32 + hi * 8];
    #pragma unroll
    for (int sj = 0; sj < 8; sj++){
      bf16x8 bk = *(const bf16x8*)&Ks[(sj * 16 + la) * 72 + kk * 32 + hi * 8];
      sc[sj] = __builtin_amdgcn_mfma_f32_16x16x32_bf16(aq, bk, sc[sj], 0, 0, 0);
    }
  }

  // ---- masked in-register softmax (row = wid*16 + hi*4 + r2, col = sj*16 + la)
  float inv[4];
  #pragma unroll
  for (int r2 = 0; r2 < 4; r2++){
    int row = wid * 16 + hi * 4 + r2;
    float mx = -1e30f;
    #pragma unroll
    for (int sj = 0; sj < 8; sj++){
      int sl = sj * 16 + la;
      bool valid = (sl >= row + 1) && (sl <= row + 64) && (t0 - 64 + sl >= 0);
      float sv = valid ? sc[sj][r2] * 0.125f : -1e30f;
      sc[sj][r2] = sv;
      mx = fmaxf(mx, sv);
    }
    #pragma unroll
    for (int o = 8; o >= 1; o >>= 1) mx = fmaxf(mx, __shfl_xor(mx, o));
    float sum = 0.0f;
    #pragma unroll
    for (int sj = 0; sj < 8; sj++){
      float p = __expf(sc[sj][r2] - mx);
      sc[sj][r2] = p;
      sum += p;
    }
    #pragma unroll
    for (int o = 8; o >= 1; o >>= 1) sum += __shfl_xor(sum, o);
    inv[r2] = 1.0f / sum;
  }

  // ---- P -> LDS (bf16), per-wave region
  unsigned short* myP = Ps[wid];
  #pragma unroll
  for (int sj = 0; sj < 8; sj++)
    #pragma unroll
    for (int r2 = 0; r2 < 4; r2++)
      myP[(hi * 4 + r2) * 136 + sj * 16 + la] = f2b(sc[sj][r2]);

  __syncthreads();

  // ---- O = P V  (A = P[16x128], B^T = Vt[64x128], 4 n-frags x 4 k-steps)
  f32x4 oacc[4];
  #pragma unroll
  for (int nj = 0; nj < 4; nj++) oacc[nj] = (f32x4){0.f, 0.f, 0.f, 0.f};
  #pragma unroll
  for (int ks = 0; ks < 4; ks++){
    bf16x8 ap = *(const bf16x8*)&myP[la * 136 + ks * 32 + hi * 8];
    #pragma unroll
    for (int nj = 0; nj < 4; nj++){
      bf16x8 bv = *(const bf16x8*)&Vt[(nj * 16 + la) * 136 + ks * 32 + hi * 8];
      oacc[nj] = __builtin_amdgcn_mfma_f32_16x16x32_bf16(ap, bv, oacc[nj], 0, 0, 0);
    }
  }

  // ---- write O (bf16, head-concat layout), scaled by 1/rowsum
  unsigned short* obase = attn + (size_t)(b * 1024 + t0) * 768 + h * 64;
  #pragma unroll
  for (int nj = 0; nj < 4; nj++)
    #pragma unroll
    for (int r2 = 0; r2 < 4; r2++){
      int row = wid * 16 + hi * 4 + r2;
      obase[(size_t)row * 768 + nj * 16 + la] = f2b(oacc[nj][r2] * inv[r2]);
    }
}

__global__ void aux_k(float* p){ if (threadIdx.x == 0) p[0] = 0.0f; }

// ----------------------------------------------------------------------------------
extern "C" void kernel_launch(void* const* d_in, const int* in_sizes, int n_in,
                              void* d_out, int out_size, void* d_ws, size_t ws_size,
                              hipStream_t stream)
{
  const float* x      = (const float*)d_in[0];
  const float* w_q    = (const float*)d_in[1];
  const float* w_k    = (const float*)d_in[2];
  const float* w_v    = (const float*)d_in[3];
  const float* w_proj = (const float*)d_in[4];
  const float* b_proj = (const float*)d_in[5];
  const float* w_ff1  = (const float*)d_in[6];
  const float* b_ff1  = (const float*)d_in[7];
  const float* w_ff2  = (const float*)d_in[8];
  const float* b_ff2  = (const float*)d_in[9];
  const float* g1     = (const float*)d_in[10];
  const float* g2     = (const float*)d_in[11];
  float* out = (float*)d_out;

  char* ws = (char*)d_ws;
  size_t off = 0;
  auto alloc = [&](size_t bytes){ size_t r = off; off += (bytes + 255) & ~(size_t)255; return r; };
  const size_t BT = 8 * 1024;  // 8192 rows

  unsigned short* h     = (unsigned short*)(ws + alloc(BT * 768 * 2));   // reused for attn out
  unsigned short* qkv   = (unsigned short*)(ws + alloc(BT * 3072 * 2));  // reused for ffa
  float*          x2    = (float*)         (ws + alloc(BT * 768 * 4));
  unsigned short* h2    = (unsigned short*)(ws + alloc(BT * 768 * 2));
  unsigned short* WqkvT = (unsigned short*)(ws + alloc(2304 * 768 * 2));
  unsigned short* WprojT= (unsigned short*)(ws + alloc(768 * 768 * 2));
  unsigned short* Wff1T = (unsigned short*)(ws + alloc(3072 * 768 * 2));
  unsigned short* Wff2T = (unsigned short*)(ws + alloc(768 * 3072 * 2));
  unsigned short* attn  = h;     // h dead after QKV GEMM
  unsigned short* ffa   = qkv;   // qkv dead after attention

  // all weights -> bf16 transposed, ONE launch
  transpose_all<<<6912, 256, 0, stream>>>(w_q, w_k, w_v, w_proj, w_ff1, w_ff2,
                                          WqkvT, WprojT, Wff1T, Wff2T);

  // h = rmsnorm(x, g1)
  rmsnorm_k<<<2048, 256, 0, stream>>>(x, g1, h);

  // qkv = h @ [Wq|Wk|Wv]   (M=8192, N=2304, K=768) — 2304 tiles, 3/block persistent
  gemm_db<3,false,false,false,false><<<768, 256, 0, stream>>>(h, WqkvT, nullptr, nullptr, qkv, 8192, 2304, 768);

  // sliding-window attention -> attn (bf16, [B*T][768] head-concat layout)
  attn_k<<<8 * 12 * 16, 256, 0, stream>>>(qkv, attn);

  // x2 = x + attn @ Wproj + b_proj   (fp32 out) — 768 tiles, 1/block
  gemm_db<1,true,false,true,true><<<768, 256, 0, stream>>>(attn, WprojT, b_proj, x, x2, 8192, 768, 768);

  // h2 = rmsnorm(x2, g2)
  rmsnorm_k<<<2048, 256, 0, stream>>>(x2, g2, h2);

  // ffa = gelu(h2 @ Wff1 + b_ff1)   (M=8192, N=3072, K=768) — 3072 tiles, 4/block
  gemm_db<4,true,true,false,false><<<768, 256, 0, stream>>>(h2, Wff1T, b_ff1, nullptr, ffa, 8192, 3072, 768);

  // out = x2 + ffa @ Wff2 + b_ff2   (M=8192, N=768, K=3072) — 768 tiles, 1/block
  gemm_db<1,true,false,true,true><<<768, 256, 0, stream>>>(ffa, Wff2T, b_ff2, x2, out, 8192, 768, 3072);

  // aux scalar
  aux_k<<<1, 64, 0, stream>>>(out + 6291456);
}

// Round 12
// 208.192 us; speedup vs baseline: 1.1836x; 1.0027x over previous
//
#include <hip/hip_runtime.h>
#include <cstdint>

#define DEVI __device__ __forceinline__

typedef __bf16 bf16x8 __attribute__((ext_vector_type(8)));
typedef float  f32x4  __attribute__((ext_vector_type(4)));
typedef float  f32x16 __attribute__((ext_vector_type(16)));

template<int V> struct IC { static constexpr int v = V; };

DEVI unsigned short f2b(float f){
  unsigned u = __builtin_bit_cast(unsigned, f);
  unsigned r = u + 0x7FFF + ((u >> 16) & 1);
  return (unsigned short)(r >> 16);
}
DEVI float b2f(unsigned short s){
  unsigned u = ((unsigned)s) << 16;
  return __builtin_bit_cast(float, u);
}
DEVI float gelu_f(float x){
  float u = 0.7978845608028654f * (x + 0.044715f * x * x * x);
  float e = __expf(2.0f * u);
  return x * (1.0f - 1.0f / (e + 1.0f));   // == 0.5x(1+tanh(u)), safe at e->inf / e->0
}
DEVI void gl_lds16(const unsigned short* g, unsigned short* l){
  __builtin_amdgcn_global_load_lds(
      (const __attribute__((address_space(1))) unsigned int*)g,
      (__attribute__((address_space(3))) unsigned int*)l, 16, 0, 0);
}

// ---------------- fused weight transpose + f32->bf16 (ONE launch for all 6) -------
__global__ __launch_bounds__(256)
void transpose_all(const float* __restrict__ w_q, const float* __restrict__ w_k,
                   const float* __restrict__ w_v, const float* __restrict__ w_proj,
                   const float* __restrict__ w_ff1, const float* __restrict__ w_ff2,
                   unsigned short* __restrict__ WqkvT, unsigned short* __restrict__ WprojT,
                   unsigned short* __restrict__ Wff1T, unsigned short* __restrict__ Wff2T)
{
  __shared__ float tile[32][33];
  int blk = blockIdx.x;
  const float* in; unsigned short* out; int R, C, b0;
  if      (blk < 576) { in = w_q;    out = WqkvT;              R = 768;  C = 768;  b0 = 0;    }
  else if (blk < 1152){ in = w_k;    out = WqkvT + 768 * 768;  R = 768;  C = 768;  b0 = 576;  }
  else if (blk < 1728){ in = w_v;    out = WqkvT + 1536 * 768; R = 768;  C = 768;  b0 = 1152; }
  else if (blk < 2304){ in = w_proj; out = WprojT;             R = 768;  C = 768;  b0 = 1728; }
  else if (blk < 4608){ in = w_ff1;  out = Wff1T;              R = 768;  C = 3072; b0 = 2304; }
  else                { in = w_ff2;  out = Wff2T;              R = 3072; C = 768;  b0 = 4608; }
  int lb = blk - b0;
  int nbx = C >> 5;
  int bx = lb % nbx, by = lb / nbx;
  int c0 = bx << 5, r0 = by << 5;
  int tx = threadIdx.x & 31, ty = threadIdx.x >> 5;   // 32 x 8
  #pragma unroll
  for (int j = 0; j < 32; j += 8)
    tile[ty + j][tx] = in[(size_t)(r0 + ty + j) * C + c0 + tx];
  __syncthreads();
  #pragma unroll
  for (int j = 0; j < 32; j += 8)
    out[(size_t)(c0 + ty + j) * R + r0 + tx] = f2b(tile[tx][ty + j]);
}

// ---------------- RMSNorm: x f32 [rows][768] -> out bf16, 1 wave per row ----------
__global__ __launch_bounds__(256)
void rmsnorm_k(const float* __restrict__ x, const float* __restrict__ g,
               unsigned short* __restrict__ out)
{
  int wid = threadIdx.x >> 6, lane = threadIdx.x & 63;
  size_t row = (size_t)blockIdx.x * 4 + wid;
  const float* xr = x + row * 768;
  float4 v[3];
  float ss = 0.0f;
  #pragma unroll
  for (int c = 0; c < 3; c++){
    v[c] = *(const float4*)&xr[lane * 4 + c * 256];
    ss += v[c].x * v[c].x + v[c].y * v[c].y + v[c].z * v[c].z + v[c].w * v[c].w;
  }
  #pragma unroll
  for (int o = 32; o >= 1; o >>= 1) ss += __shfl_xor(ss, o);
  float rs = rsqrtf(ss * (1.0f / 768.0f) + 1e-6f);
  #pragma unroll
  for (int c = 0; c < 3; c++){
    const float4 gv = *(const float4*)&g[lane * 4 + c * 256];
    ushort4 o4;
    o4.x = f2b(v[c].x * rs * gv.x);
    o4.y = f2b(v[c].y * rs * gv.y);
    o4.z = f2b(v[c].z * rs * gv.z);
    o4.w = f2b(v[c].w * rs * gv.w);
    *(ushort4*)&out[row * 768 + lane * 4 + c * 256] = o4;
  }
}

// ---------------- GEMM 64x128 PERSISTENT (r11, unchanged) -------------------------
template<int TPB, bool BIAS, bool GELU_, bool RES, bool OUTF32>
__global__ __launch_bounds__(256, 3)
void gemm_db(const unsigned short* __restrict__ A, const unsigned short* __restrict__ Bt,
             const float* __restrict__ bias, const float* __restrict__ res,
             void* __restrict__ outp, int M, int N, int K)
{
  constexpr int BM = 64;
  constexpr int MI = 2;                   // m-frags per wave
  constexpr int AL = 2;                   // A-stage instrs per wave
  constexpr int BUFSZ = (BM + 128) * 64;  // shorts per buffer
  __shared__ unsigned short sm[2][BUFSZ];

  int tid = threadIdx.x, wid = tid >> 6, lane = tid & 63;
  int la = lane & 15, hi = lane >> 4;
  int wm = wid >> 1, wn = wid & 1;        // 2x2 waves
  int tiles_n = N >> 7;
  int bid = blockIdx.x;
  bid = (bid & 7) * (gridDim.x >> 3) + (bid >> 3);   // XCD-aware swizzle
  int g0 = bid * TPB;                     // first output tile (consecutive: A reuse)
  int NT = K >> 6;

  size_t constA[AL]; unsigned short* aDst[2][AL];
  size_t constB[4];  unsigned short* bDst[2][4];
  #pragma unroll
  for (int l = 0; l < AL; l++){
    int cb = wid * (BM * 2) + l * 64;
    int idx = cb + lane;
    int row = idx >> 3, sl2 = (idx & 7) ^ (row & 7);
    constA[l] = (size_t)row * K + sl2 * 8;
    aDst[0][l] = &sm[0][cb * 8];
    aDst[1][l] = &sm[1][cb * 8];
  }
  #pragma unroll
  for (int l = 0; l < 4; l++){
    int cb = wid * 256 + l * 64;
    int idx = cb + lane;
    int row = idx >> 3, sl2 = (idx & 7) ^ (row & 7);
    constB[l] = (size_t)row * K + sl2 * 8;
    bDst[0][l] = &sm[0][BM * 64 + cb * 8];
    bDst[1][l] = &sm[1][BM * 64 + cb * 8];
  }

  const unsigned short* fa[2][2];
  const unsigned short* fb[2][2];
  #pragma unroll
  for (int bf = 0; bf < 2; bf++)
    #pragma unroll
    for (int kk = 0; kk < 2; kk++){
      int sw = (((kk * 4 + hi) ^ (la & 7))) * 8;
      fa[bf][kk] = &sm[bf][(wm * (BM / 2) + la) * 64 + sw];
      fb[bf][kk] = &sm[bf][BM * 64 + (wn * 64 + la) * 64 + sw];
    }

  const unsigned short* aSrc[AL];
  const unsigned short* bSrc[4];
  auto setSrc = [&](int g){
    int m0 = (g / tiles_n) * BM, n0 = (g % tiles_n) << 7;
    #pragma unroll
    for (int l = 0; l < AL; l++) aSrc[l] = A  + (size_t)m0 * K + constA[l];
    #pragma unroll
    for (int l = 0; l < 4;  l++) bSrc[l] = Bt + (size_t)n0 * K + constB[l];
  };
  auto stageTo = [&](auto BF){
    constexpr int bf = decltype(BF)::v;
    #pragma unroll
    for (int l = 0; l < AL; l++){ gl_lds16(aSrc[l], aDst[bf][l]); aSrc[l] += 64; }
    #pragma unroll
    for (int l = 0; l < 4; l++){ gl_lds16(bSrc[l], bDst[bf][l]); bSrc[l] += 64; }
  };

  setSrc(g0);
  stageTo(IC<0>{});

  float* outF = (float*)outp;
  unsigned short* outB = (unsigned short*)outp;

  for (int ot = 0; ot < TPB; ot++){
    int g = g0 + ot;
    int m0 = (g / tiles_n) * BM, n0 = (g % tiles_n) << 7;

    f32x4 acc[MI][4] = {};

    auto tile_step = [&](auto BUF, int t){
      constexpr int CB = decltype(BUF)::v;
      if (t + 1 < NT || ot + 1 < TPB){
        if (t + 1 == NT) setSrc(g + 1);
        stageTo(IC<CB ^ 1>{});
        asm volatile("s_waitcnt vmcnt(6)" ::: "memory");
      } else {
        asm volatile("s_waitcnt vmcnt(0)" ::: "memory");
      }
      __builtin_amdgcn_s_barrier();

      bf16x8 afr[MI][2], bfr[4][2];
      #pragma unroll
      for (int mm = 0; mm < MI; mm++){
        afr[mm][0] = *(const bf16x8*)(fa[CB][0] + mm * 1024);
        afr[mm][1] = *(const bf16x8*)(fa[CB][1] + mm * 1024);
      }
      #pragma unroll
      for (int nn = 0; nn < 4; nn++){
        bfr[nn][0] = *(const bf16x8*)(fb[CB][0] + nn * 1024);
        bfr[nn][1] = *(const bf16x8*)(fb[CB][1] + nn * 1024);
      }
      __builtin_amdgcn_s_setprio(1);
      #pragma unroll
      for (int mm = 0; mm < MI; mm++)
        #pragma unroll
        for (int nn = 0; nn < 4; nn++)
          #pragma unroll
          for (int kk = 0; kk < 2; kk++)
            acc[mm][nn] = __builtin_amdgcn_mfma_f32_16x16x32_bf16(
                afr[mm][kk], bfr[nn][kk], acc[mm][nn], 0, 0, 0);
      __builtin_amdgcn_s_setprio(0);

      __builtin_amdgcn_s_barrier();
    };

    for (int t = 0; t < NT; t += 2){
      tile_step(IC<0>{}, t);
      tile_step(IC<1>{}, t + 1);
    }

    #pragma unroll
    for (int mm = 0; mm < MI; mm++){
      int rowb = m0 + wm * (BM / 2) + mm * 16 + hi * 4;
      #pragma unroll
      for (int nn = 0; nn < 4; nn++){
        int col = n0 + wn * 64 + nn * 16 + la;
        float bv = BIAS ? bias[col] : 0.0f;
        #pragma unroll
        for (int r = 0; r < 4; r++){
          float val = acc[mm][nn][r] + bv;
          if (GELU_) val = gelu_f(val);
          if (RES)   val += res[(size_t)(rowb + r) * N + col];
          size_t o = (size_t)(rowb + r) * N + col;
          if (OUTF32) outF[o] = val;
          else        outB[o] = f2b(val);
        }
      }
    }
  }
}

// ---------------- GEMM 128x128, 32x32x16 MFMA, persistent -------------------------
// 4 waves 2x2, per-wave 64x64 = 2x2 frags of 32x32x16: 32 FLOP per LDS byte (1.5x
// the 16x16 BM=64 shape) and HALF the MFMA instruction count. LDS 64 KB dbuf ->
// 2 blocks/CU. Same XOR swizzle / hoisted addressing / counted vmcnt(8) / TPB
// persistence as gemm_db. A frag: row=lane&31, k=8*(lane>>5)+j (2x analog of the
// verified 16x16x32 layout); C/D: col=lane&31, row=(reg&3)+8*(reg>>2)+4*(lane>>5)
// [m74/m101-verified]. Requires M%128==0, N%128==0, K%128==0, grid%8==0.
template<int TPB, bool BIAS, bool GELU_, bool OUTF32>
__global__ __launch_bounds__(256, 2)
void gemm32(const unsigned short* __restrict__ A, const unsigned short* __restrict__ Bt,
            const float* __restrict__ bias, void* __restrict__ outp,
            int M, int N, int K)
{
  __shared__ unsigned short sm[2][16384];   // [buf][ A: 0..8191 | B: 8192..16383 ]
  int tid = threadIdx.x, wid = tid >> 6, lane = tid & 63;
  int l31 = lane & 31, hi2 = lane >> 5;
  int wm = wid >> 1, wn = wid & 1;
  int tiles_n = N >> 7;
  int bid = blockIdx.x;
  bid = (bid & 7) * (gridDim.x >> 3) + (bid >> 3);   // XCD-aware swizzle
  int g0 = bid * TPB;
  int NT = K >> 6;

  f32x16 acc[2][2];

  // ---- hoisted stage addressing (per-lane src offsets; wave-uniform dests)
  size_t constA[4], constB[4];
  #pragma unroll
  for (int l = 0; l < 4; l++){
    int cb = wid * 256 + l * 64;
    int idx = cb + lane;
    int row = idx >> 3, sl2 = (idx & 7) ^ (row & 7);
    constA[l] = (size_t)row * K + sl2 * 8;
    constB[l] = (size_t)row * K + sl2 * 8;
  }

  // ---- hoisted fragment addressing: per-lane row base + per-kstep swizzled offset
  int aRow = (wm * 64 + l31) * 64;          // shorts
  int bRow = (wn * 64 + l31) * 64;
  int swk[4];
  #pragma unroll
  for (int ks = 0; ks < 4; ks++)
    swk[ks] = (((ks * 2 + hi2) ^ (l31 & 7))) * 8;

  const unsigned short* aSrc[4];
  const unsigned short* bSrc[4];
  auto setSrc = [&](int g){
    int m0 = (g / tiles_n) << 7, n0 = (g % tiles_n) << 7;
    #pragma unroll
    for (int l = 0; l < 4; l++){
      aSrc[l] = A  + (size_t)m0 * K + constA[l];
      bSrc[l] = Bt + (size_t)n0 * K + constB[l];
    }
  };
  auto stageTo = [&](auto BF){
    constexpr int bf = decltype(BF)::v;
    #pragma unroll
    for (int l = 0; l < 4; l++){
      gl_lds16(aSrc[l], &sm[bf][wid * 2048 + l * 512]);        aSrc[l] += 64;
    }
    #pragma unroll
    for (int l = 0; l < 4; l++){
      gl_lds16(bSrc[l], &sm[bf][8192 + wid * 2048 + l * 512]); bSrc[l] += 64;
    }
  };

  setSrc(g0);
  stageTo(IC<0>{});                         // ONE cold start per block

  float* outF = (float*)outp;
  unsigned short* outB = (unsigned short*)outp;

  for (int ot = 0; ot < TPB; ot++){
    int g = g0 + ot;
    int m0 = (g / tiles_n) << 7, n0 = (g % tiles_n) << 7;

    #pragma unroll
    for (int mi = 0; mi < 2; mi++)
      #pragma unroll
      for (int nn = 0; nn < 2; nn++)
        acc[mi][nn] = (f32x16){};

    auto tile_step = [&](auto BUF, int t){
      constexpr int CB = decltype(BUF)::v;
      if (t + 1 < NT || ot + 1 < TPB){
        if (t + 1 == NT) setSrc(g + 1);
        stageTo(IC<CB ^ 1>{});
        asm volatile("s_waitcnt vmcnt(8)" ::: "memory");   // stage(t) landed
      } else {
        asm volatile("s_waitcnt vmcnt(0)" ::: "memory");
      }
      __builtin_amdgcn_s_barrier();

      const unsigned short* As = sm[CB];
      const unsigned short* Bs = sm[CB] + 8192;
      bf16x8 av[2][4], bv[2][4];
      #pragma unroll
      for (int ks = 0; ks < 4; ks++){
        #pragma unroll
        for (int mi = 0; mi < 2; mi++)
          av[mi][ks] = *(const bf16x8*)&As[aRow + mi * 2048 + swk[ks]];
        #pragma unroll
        for (int nn = 0; nn < 2; nn++)
          bv[nn][ks] = *(const bf16x8*)&Bs[bRow + nn * 2048 + swk[ks]];
      }
      __builtin_amdgcn_s_setprio(1);
      #pragma unroll
      for (int ks = 0; ks < 4; ks++)
        #pragma unroll
        for (int mi = 0; mi < 2; mi++)
          #pragma unroll
          for (int nn = 0; nn < 2; nn++)
            acc[mi][nn] = __builtin_amdgcn_mfma_f32_32x32x16_bf16(
                av[mi][ks], bv[nn][ks], acc[mi][nn], 0, 0, 0);
      __builtin_amdgcn_s_setprio(0);

      __builtin_amdgcn_s_barrier();
    };

    for (int t = 0; t < NT; t += 2){        // NT even (K%128==0)
      tile_step(IC<0>{}, t);
      tile_step(IC<1>{}, t + 1);
    }

    // ---- epilogue: C/D 32x32 layout col=lane&31, row=(reg&3)+8*(reg>>2)+4*hi2
    #pragma unroll
    for (int mi = 0; mi < 2; mi++){
      #pragma unroll
      for (int nn = 0; nn < 2; nn++){
        int col = n0 + wn * 64 + nn * 32 + l31;
        float bvs = BIAS ? bias[col] : 0.0f;
        #pragma unroll
        for (int reg = 0; reg < 16; reg++){
          int row = m0 + wm * 64 + mi * 32 + (reg & 3) + 8 * (reg >> 2) + 4 * hi2;
          float val = acc[mi][nn][reg] + bvs;
          if (GELU_) val = gelu_f(val);
          size_t o = (size_t)row * N + col;
          if (OUTF32) outF[o] = val;
          else        outB[o] = f2b(val);
        }
      }
    }
  }
}

// ---------------- sliding-window causal attention, W=64, D=64, MFMA tile ----------
__global__ __launch_bounds__(256)
void attn_k(const unsigned short* __restrict__ qkv, unsigned short* __restrict__ attn)
{
  __shared__ unsigned short Qs[64 * 72];       // stride 72: b128 reads at 8-way min
  __shared__ unsigned short Ks[128 * 72];
  __shared__ unsigned short Vt[64 * 136];      // V^T [d][s], stride 136
  __shared__ unsigned short Ps[4][16 * 136];   // per-wave P rows

  int tid = threadIdx.x, wid = tid >> 6, lane = tid & 63;
  int la = lane & 15, hi = lane >> 4;
  int blk = blockIdx.x;
  blk = (blk & 7) * (gridDim.x >> 3) + (blk >> 3);   // XCD swizzle (1536 % 8 == 0)
  int tile = blk & 15, hb = blk >> 4;
  int h = hb % 12, b = hb / 12;
  int t0 = tile << 6;

  const unsigned short* qbase = qkv + (size_t)(b * 1024) * 2304 + h * 64;

  // ---- stage Q: 64 rows x 8 chunks of 8 bf16
  #pragma unroll
  for (int r = 0; r < 2; r++){
    int idx = tid + r * 256;
    int row = idx >> 3, ch = idx & 7;
    uint4 v = *(const uint4*)(qbase + (size_t)(t0 + row) * 2304 + ch * 8);
    *(uint4*)&Qs[row * 72 + ch * 8] = v;
  }
  // ---- stage K: 128 rows (clamped at s_global<0; masked later)
  #pragma unroll
  for (int r = 0; r < 4; r++){
    int idx = tid + r * 256;
    int row = idx >> 3, ch = idx & 7;
    int sg = t0 - 64 + row; sg = sg < 0 ? 0 : sg;
    uint4 v = *(const uint4*)(qbase + 768 + (size_t)sg * 2304 + ch * 8);
    *(uint4*)&Ks[row * 72 + ch * 8] = v;
  }
  // ---- stage V transposed (s-major lane assignment -> 2-way LDS writes)
  #pragma unroll
  for (int r = 0; r < 4; r++){
    int idx = tid + r * 256;
    int s = idx & 127, ch = idx >> 7;
    int sg = t0 - 64 + s; sg = sg < 0 ? 0 : sg;
    uint4 v = *(const uint4*)(qbase + 1536 + (size_t)sg * 2304 + ch * 8);
    unsigned short tmp[8];
    *(uint4*)tmp = v;
    #pragma unroll
    for (int j = 0; j < 8; j++)
      Vt[(ch * 8 + j) * 136 + s] = tmp[j];
  }
  __syncthreads();

  // ---- S = Q K^T for 16 own rows x 128 cols (8 col-fragments x 2 k-steps)
  f32x4 sc[8];
  #pragma unroll
  for (int sj = 0; sj < 8; sj++) sc[sj] = (f32x4){0.f, 0.f, 0.f, 0.f};
  #pragma unroll
  for (int kk = 0; kk < 2; kk++){
    bf16x8 aq = *(const bf16x8*)&Qs[(wid * 16 + la) * 72 + kk * 32 + hi * 8];
    #pragma unroll
    for (int sj = 0; sj < 8; sj++){
      bf16x8 bk = *(const bf16x8*)&Ks[(sj * 16 + la) * 72 + kk * 32 + hi * 8];
      sc[sj] = __builtin_amdgcn_mfma_f32_16x16x32_bf16(aq, bk, sc[sj], 0, 0, 0);
    }
  }

  // ---- masked in-register softmax (row = wid*16 + hi*4 + r2, col = sj*16 + la)
  float inv[4];
  #pragma unroll
  for (int r2 = 0; r2 < 4; r2++){
    int row = wid * 16 + hi * 4 + r2;
    float mx = -1e30f;
    #pragma unroll
    for (int sj = 0; sj < 8; sj++){
      int sl = sj * 16 + la;
      bool valid = (sl >= row + 1) && (sl <= row + 64) && (t0 - 64 + sl >= 0);
      float sv = valid ? sc[sj][r2] * 0.125f : -1e30f;
      sc[sj][r2] = sv;
      mx = fmaxf(mx, sv);
    }
    #pragma unroll
    for (int o = 8; o >= 1; o >>= 1) mx = fmaxf(mx, __shfl_xor(mx, o));
    float sum = 0.0f;
    #pragma unroll
    for (int sj = 0; sj < 8; sj++){
      float p = __expf(sc[sj][r2] - mx);
      sc[sj][r2] = p;
      sum += p;
    }
    #pragma unroll
    for (int o = 8; o >= 1; o >>= 1) sum += __shfl_xor(sum, o);
    inv[r2] = 1.0f / sum;
  }

  // ---- P -> LDS (bf16), per-wave region
  unsigned short* myP = Ps[wid];
  #pragma unroll
  for (int sj = 0; sj < 8; sj++)
    #pragma unroll
    for (int r2 = 0; r2 < 4; r2++)
      myP[(hi * 4 + r2) * 136 + sj * 16 + la] = f2b(sc[sj][r2]);

  __syncthreads();

  // ---- O = P V  (A = P[16x128], B^T = Vt[64x128], 4 n-frags x 4 k-steps)
  f32x4 oacc[4];
  #pragma unroll
  for (int nj = 0; nj < 4; nj++) oacc[nj] = (f32x4){0.f, 0.f, 0.f, 0.f};
  #pragma unroll
  for (int ks = 0; ks < 4; ks++){
    bf16x8 ap = *(const bf16x8*)&myP[la * 136 + ks * 32 + hi * 8];
    #pragma unroll
    for (int nj = 0; nj < 4; nj++){
      bf16x8 bv = *(const bf16x8*)&Vt[(nj * 16 + la) * 136 + ks * 32 + hi * 8];
      oacc[nj] = __builtin_amdgcn_mfma_f32_16x16x32_bf16(ap, bv, oacc[nj], 0, 0, 0);
    }
  }

  // ---- write O (bf16, head-concat layout), scaled by 1/rowsum
  unsigned short* obase = attn + (size_t)(b * 1024 + t0) * 768 + h * 64;
  #pragma unroll
  for (int nj = 0; nj < 4; nj++)
    #pragma unroll
    for (int r2 = 0; r2 < 4; r2++){
      int row = wid * 16 + hi * 4 + r2;
      obase[(size_t)row * 768 + nj * 16 + la] = f2b(oacc[nj][r2] * inv[r2]);
    }
}

__global__ void aux_k(float* p){ if (threadIdx.x == 0) p[0] = 0.0f; }

// ----------------------------------------------------------------------------------
extern "C" void kernel_launch(void* const* d_in, const int* in_sizes, int n_in,
                              void* d_out, int out_size, void* d_ws, size_t ws_size,
                              hipStream_t stream)
{
  const float* x      = (const float*)d_in[0];
  const float* w_q    = (const float*)d_in[1];
  const float* w_k    = (const float*)d_in[2];
  const float* w_v    = (const float*)d_in[3];
  const float* w_proj = (const float*)d_in[4];
  const float* b_proj = (const float*)d_in[5];
  const float* w_ff1  = (const float*)d_in[6];
  const float* b_ff1  = (const float*)d_in[7];
  const float* w_ff2  = (const float*)d_in[8];
  const float* b_ff2  = (const float*)d_in[9];
  const float* g1     = (const float*)d_in[10];
  const float* g2     = (const float*)d_in[11];
  float* out = (float*)d_out;

  char* ws = (char*)d_ws;
  size_t off = 0;
  auto alloc = [&](size_t bytes){ size_t r = off; off += (bytes + 255) & ~(size_t)255; return r; };
  const size_t BT = 8 * 1024;  // 8192 rows

  unsigned short* h     = (unsigned short*)(ws + alloc(BT * 768 * 2));   // reused for attn out
  unsigned short* qkv   = (unsigned short*)(ws + alloc(BT * 3072 * 2));  // reused for ffa
  float*          x2    = (float*)         (ws + alloc(BT * 768 * 4));
  unsigned short* h2    = (unsigned short*)(ws + alloc(BT * 768 * 2));
  unsigned short* WqkvT = (unsigned short*)(ws + alloc(2304 * 768 * 2));
  unsigned short* WprojT= (unsigned short*)(ws + alloc(768 * 768 * 2));
  unsigned short* Wff1T = (unsigned short*)(ws + alloc(3072 * 768 * 2));
  unsigned short* Wff2T = (unsigned short*)(ws + alloc(768 * 3072 * 2));
  unsigned short* attn  = h;     // h dead after QKV GEMM
  unsigned short* ffa   = qkv;   // qkv dead after attention

  // all weights -> bf16 transposed, ONE launch
  transpose_all<<<6912, 256, 0, stream>>>(w_q, w_k, w_v, w_proj, w_ff1, w_ff2,
                                          WqkvT, WprojT, Wff1T, Wff2T);

  // h = rmsnorm(x, g1)
  rmsnorm_k<<<2048, 256, 0, stream>>>(x, g1, h);

  // qkv = h @ [Wq|Wk|Wv]   (M=8192, N=2304, K=768) — 2304 tiles, 3/block persistent
  gemm_db<3,false,false,false,false><<<768, 256, 0, stream>>>(h, WqkvT, nullptr, nullptr, qkv, 8192, 2304, 768);

  // sliding-window attention -> attn (bf16, [B*T][768] head-concat layout)
  attn_k<<<8 * 12 * 16, 256, 0, stream>>>(qkv, attn);

  // x2 = x + attn @ Wproj + b_proj   (fp32 out) — 768 tiles, 1/block
  gemm_db<1,true,false,true,true><<<768, 256, 0, stream>>>(attn, WprojT, b_proj, x, x2, 8192, 768, 768);

  // h2 = rmsnorm(x2, g2)
  rmsnorm_k<<<2048, 256, 0, stream>>>(x2, g2, h2);

  // ffa = gelu(h2 @ Wff1 + b_ff1)   (M=8192, N=3072, K=768) — 32x32 MFMA kernel,
  // 1536 tiles of 128x128, grid 512 = exact 2-blocks/CU round, TPB=3 (shared A)
  gemm32<3,true,true,false><<<512, 256, 0, stream>>>(h2, Wff1T, b_ff1, ffa, 8192, 3072, 768);

  // out = x2 + ffa @ Wff2 + b_ff2   (M=8192, N=768, K=3072) — 768 tiles, 1/block
  gemm_db<1,true,false,true,true><<<768, 256, 0, stream>>>(ffa, Wff2T, b_ff2, x2, out, 8192, 768, 3072);

  // aux scalar
  aux_k<<<1, 64, 0, stream>>>(out + 6291456);
}

// Round 13
// 205.319 us; speedup vs baseline: 1.2001x; 1.0140x over previous
//
#include <hip/hip_runtime.h>
#include <cstdint>

#define DEVI __device__ __forceinline__

typedef __bf16 bf16x8 __attribute__((ext_vector_type(8)));
typedef float  f32x4  __attribute__((ext_vector_type(4)));

template<int V> struct IC { static constexpr int v = V; };

DEVI unsigned short f2b(float f){
  unsigned u = __builtin_bit_cast(unsigned, f);
  unsigned r = u + 0x7FFF + ((u >> 16) & 1);
  return (unsigned short)(r >> 16);
}
DEVI float b2f(unsigned short s){
  unsigned u = ((unsigned)s) << 16;
  return __builtin_bit_cast(float, u);
}
DEVI float gelu_f(float x){
  float u = 0.7978845608028654f * (x + 0.044715f * x * x * x);
  float e = __expf(2.0f * u);
  return x * (1.0f - 1.0f / (e + 1.0f));   // == 0.5x(1+tanh(u)), safe at e->inf / e->0
}
DEVI void gl_lds16(const unsigned short* g, unsigned short* l){
  __builtin_amdgcn_global_load_lds(
      (const __attribute__((address_space(1))) unsigned int*)g,
      (__attribute__((address_space(3))) unsigned int*)l, 16, 0, 0);
}

// ---------------- fused weight transpose + f32->bf16 (ONE launch for all 6) -------
__global__ __launch_bounds__(256)
void transpose_all(const float* __restrict__ w_q, const float* __restrict__ w_k,
                   const float* __restrict__ w_v, const float* __restrict__ w_proj,
                   const float* __restrict__ w_ff1, const float* __restrict__ w_ff2,
                   unsigned short* __restrict__ WqkvT, unsigned short* __restrict__ WprojT,
                   unsigned short* __restrict__ Wff1T, unsigned short* __restrict__ Wff2T)
{
  __shared__ float tile[32][33];
  int blk = blockIdx.x;
  const float* in; unsigned short* out; int R, C, b0;
  if      (blk < 576) { in = w_q;    out = WqkvT;              R = 768;  C = 768;  b0 = 0;    }
  else if (blk < 1152){ in = w_k;    out = WqkvT + 768 * 768;  R = 768;  C = 768;  b0 = 576;  }
  else if (blk < 1728){ in = w_v;    out = WqkvT + 1536 * 768; R = 768;  C = 768;  b0 = 1152; }
  else if (blk < 2304){ in = w_proj; out = WprojT;             R = 768;  C = 768;  b0 = 1728; }
  else if (blk < 4608){ in = w_ff1;  out = Wff1T;              R = 768;  C = 3072; b0 = 2304; }
  else                { in = w_ff2;  out = Wff2T;              R = 3072; C = 768;  b0 = 4608; }
  int lb = blk - b0;
  int nbx = C >> 5;
  int bx = lb % nbx, by = lb / nbx;
  int c0 = bx << 5, r0 = by << 5;
  int tx = threadIdx.x & 31, ty = threadIdx.x >> 5;   // 32 x 8
  #pragma unroll
  for (int j = 0; j < 32; j += 8)
    tile[ty + j][tx] = in[(size_t)(r0 + ty + j) * C + c0 + tx];
  __syncthreads();
  #pragma unroll
  for (int j = 0; j < 32; j += 8)
    out[(size_t)(c0 + ty + j) * R + r0 + tx] = f2b(tile[tx][ty + j]);
}

// ---------------- RMSNorm: x f32 [rows][768] -> out bf16, 1 wave per row ----------
__global__ __launch_bounds__(256)
void rmsnorm_k(const float* __restrict__ x, const float* __restrict__ g,
               unsigned short* __restrict__ out)
{
  int wid = threadIdx.x >> 6, lane = threadIdx.x & 63;
  size_t row = (size_t)blockIdx.x * 4 + wid;
  const float* xr = x + row * 768;
  float4 v[3];
  float ss = 0.0f;
  #pragma unroll
  for (int c = 0; c < 3; c++){
    v[c] = *(const float4*)&xr[lane * 4 + c * 256];
    ss += v[c].x * v[c].x + v[c].y * v[c].y + v[c].z * v[c].z + v[c].w * v[c].w;
  }
  #pragma unroll
  for (int o = 32; o >= 1; o >>= 1) ss += __shfl_xor(ss, o);
  float rs = rsqrtf(ss * (1.0f / 768.0f) + 1e-6f);
  #pragma unroll
  for (int c = 0; c < 3; c++){
    const float4 gv = *(const float4*)&g[lane * 4 + c * 256];
    ushort4 o4;
    o4.x = f2b(v[c].x * rs * gv.x);
    o4.y = f2b(v[c].y * rs * gv.y);
    o4.z = f2b(v[c].z * rs * gv.z);
    o4.w = f2b(v[c].w * rs * gv.w);
    *(ushort4*)&out[row * 768 + lane * 4 + c * 256] = o4;
  }
}

// ---------------- GEMM 64x128 PERSISTENT, ONE-barrier-per-tile pipeline -----------
// r11 structure (BM=64, BK=64, dbuf, XOR swizzle, hoisted addr, TPB persistence),
// restructured to 1 barrier + 1 wait per K-tile:
//   tile t: vmcnt(0) [drains stage(t), issued a FULL tile earlier — same wait set
//   as r11's vmcnt(6)] -> barrier -> sched_barrier -> stage(t+1) -> ds_reads ->
//   MFMA. Race ledger: stage(t+1) writes buf[(t+1)&1]; its last readers were
//   compute(t-1), whose ds_reads were consumed before MFMA(t-1), hence before
//   barrier(t), which precedes the DMA (sched_barrier pins it). stage(t-1)'s DMAs
//   were drained by tile(t-1)'s vmcnt(0). Epilogue stores drain harmlessly at the
//   next tile's vmcnt(0). Parity continuous across output tiles (NT even).
// Requires M%64==0, N%128==0, K%128==0, grid%8==0, grid*TPB == total tiles.
template<int TPB, bool BIAS, bool GELU_, bool RES, bool OUTF32>
__global__ __launch_bounds__(256, 3)
void gemm_db(const unsigned short* __restrict__ A, const unsigned short* __restrict__ Bt,
             const float* __restrict__ bias, const float* __restrict__ res,
             void* __restrict__ outp, int M, int N, int K)
{
  constexpr int BM = 64;
  constexpr int MI = 2;                   // m-frags per wave
  constexpr int AL = 2;                   // A-stage instrs per wave
  constexpr int BUFSZ = (BM + 128) * 64;  // shorts per buffer
  __shared__ unsigned short sm[2][BUFSZ];

  int tid = threadIdx.x, wid = tid >> 6, lane = tid & 63;
  int la = lane & 15, hi = lane >> 4;
  int wm = wid >> 1, wn = wid & 1;        // 2x2 waves
  int tiles_n = N >> 7;
  int bid = blockIdx.x;
  bid = (bid & 7) * (gridDim.x >> 3) + (bid >> 3);   // XCD-aware swizzle
  int g0 = bid * TPB;                     // consecutive tiles: same A-stripe (L2 reuse)
  int NT = K >> 6;

  size_t constA[AL]; unsigned short* aDst[2][AL];
  size_t constB[4];  unsigned short* bDst[2][4];
  #pragma unroll
  for (int l = 0; l < AL; l++){
    int cb = wid * (BM * 2) + l * 64;
    int idx = cb + lane;
    int row = idx >> 3, sl2 = (idx & 7) ^ (row & 7);
    constA[l] = (size_t)row * K + sl2 * 8;
    aDst[0][l] = &sm[0][cb * 8];
    aDst[1][l] = &sm[1][cb * 8];
  }
  #pragma unroll
  for (int l = 0; l < 4; l++){
    int cb = wid * 256 + l * 64;
    int idx = cb + lane;
    int row = idx >> 3, sl2 = (idx & 7) ^ (row & 7);
    constB[l] = (size_t)row * K + sl2 * 8;
    bDst[0][l] = &sm[0][BM * 64 + cb * 8];
    bDst[1][l] = &sm[1][BM * 64 + cb * 8];
  }

  const unsigned short* fa[2][2];
  const unsigned short* fb[2][2];
  #pragma unroll
  for (int bf = 0; bf < 2; bf++)
    #pragma unroll
    for (int kk = 0; kk < 2; kk++){
      int sw = (((kk * 4 + hi) ^ (la & 7))) * 8;
      fa[bf][kk] = &sm[bf][(wm * (BM / 2) + la) * 64 + sw];
      fb[bf][kk] = &sm[bf][BM * 64 + (wn * 64 + la) * 64 + sw];
    }

  const unsigned short* aSrc[AL];
  const unsigned short* bSrc[4];
  auto setSrc = [&](int g){
    int m0 = (g / tiles_n) * BM, n0 = (g % tiles_n) << 7;
    #pragma unroll
    for (int l = 0; l < AL; l++) aSrc[l] = A  + (size_t)m0 * K + constA[l];
    #pragma unroll
    for (int l = 0; l < 4;  l++) bSrc[l] = Bt + (size_t)n0 * K + constB[l];
  };
  auto stageTo = [&](auto BF){
    constexpr int bf = decltype(BF)::v;
    #pragma unroll
    for (int l = 0; l < AL; l++){ gl_lds16(aSrc[l], aDst[bf][l]); aSrc[l] += 64; }
    #pragma unroll
    for (int l = 0; l < 4; l++){ gl_lds16(bSrc[l], bDst[bf][l]); bSrc[l] += 64; }
  };

  setSrc(g0);
  stageTo(IC<0>{});                       // ONE cold start per block

  float* outF = (float*)outp;
  unsigned short* outB = (unsigned short*)outp;

  for (int ot = 0; ot < TPB; ot++){
    int g = g0 + ot;
    int m0 = (g / tiles_n) * BM, n0 = (g % tiles_n) << 7;

    f32x4 acc[MI][4] = {};

    auto tile_step = [&](auto BUF, int t){
      constexpr int CB = decltype(BUF)::v;
      // drain stage(t) — issued one full tile ago (cold only at block start)
      asm volatile("s_waitcnt vmcnt(0)" ::: "memory");
      __builtin_amdgcn_s_barrier();                     // buf[CB] visible; buf[CB^1]
      __builtin_amdgcn_sched_barrier(0);                //   readers all done
      if (t + 1 < NT || ot + 1 < TPB){
        if (t + 1 == NT) setSrc(g + 1);                 // cross into next tile's K=0
        stageTo(IC<CB ^ 1>{});
      }

      bf16x8 afr[MI][2], bfr[4][2];
      #pragma unroll
      for (int mm = 0; mm < MI; mm++){
        afr[mm][0] = *(const bf16x8*)(fa[CB][0] + mm * 1024);
        afr[mm][1] = *(const bf16x8*)(fa[CB][1] + mm * 1024);
      }
      #pragma unroll
      for (int nn = 0; nn < 4; nn++){
        bfr[nn][0] = *(const bf16x8*)(fb[CB][0] + nn * 1024);
        bfr[nn][1] = *(const bf16x8*)(fb[CB][1] + nn * 1024);
      }
      __builtin_amdgcn_s_setprio(1);
      #pragma unroll
      for (int mm = 0; mm < MI; mm++)
        #pragma unroll
        for (int nn = 0; nn < 4; nn++)
          #pragma unroll
          for (int kk = 0; kk < 2; kk++)
            acc[mm][nn] = __builtin_amdgcn_mfma_f32_16x16x32_bf16(
                afr[mm][kk], bfr[nn][kk], acc[mm][nn], 0, 0, 0);
      __builtin_amdgcn_s_setprio(0);
      // no end-of-tile barrier: next tile's vmcnt(0)+barrier provides the fence
    };

    for (int t = 0; t < NT; t += 2){                    // NT even (K%128==0)
      tile_step(IC<0>{}, t);
      tile_step(IC<1>{}, t + 1);
    }

    // ---- epilogue for tile g (stores drain at next tile's vmcnt(0))
    #pragma unroll
    for (int mm = 0; mm < MI; mm++){
      int rowb = m0 + wm * (BM / 2) + mm * 16 + hi * 4;
      #pragma unroll
      for (int nn = 0; nn < 4; nn++){
        int col = n0 + wn * 64 + nn * 16 + la;
        float bv = BIAS ? bias[col] : 0.0f;
        #pragma unroll
        for (int r = 0; r < 4; r++){
          float val = acc[mm][nn][r] + bv;
          if (GELU_) val = gelu_f(val);
          if (RES)   val += res[(size_t)(rowb + r) * N + col];
          size_t o = (size_t)(rowb + r) * N + col;
          if (OUTF32) outF[o] = val;
          else        outB[o] = f2b(val);
        }
      }
    }
  }
}

// ---------------- sliding-window causal attention, W=64, D=64, MFMA tile ----------
__global__ __launch_bounds__(256)
void attn_k(const unsigned short* __restrict__ qkv, unsigned short* __restrict__ attn)
{
  __shared__ unsigned short Qs[64 * 72];       // stride 72: b128 reads at 8-way min
  __shared__ unsigned short Ks[128 * 72];
  __shared__ unsigned short Vt[64 * 136];      // V^T [d][s], stride 136
  __shared__ unsigned short Ps[4][16 * 136];   // per-wave P rows

  int tid = threadIdx.x, wid = tid >> 6, lane = tid & 63;
  int la = lane & 15, hi = lane >> 4;
  int blk = blockIdx.x;
  blk = (blk & 7) * (gridDim.x >> 3) + (blk >> 3);   // XCD swizzle (1536 % 8 == 0)
  int tile = blk & 15, hb = blk >> 4;
  int h = hb % 12, b = hb / 12;
  int t0 = tile << 6;

  const unsigned short* qbase = qkv + (size_t)(b * 1024) * 2304 + h * 64;

  // ---- stage Q: 64 rows x 8 chunks of 8 bf16
  #pragma unroll
  for (int r = 0; r < 2; r++){
    int idx = tid + r * 256;
    int row = idx >> 3, ch = idx & 7;
    uint4 v = *(const uint4*)(qbase + (size_t)(t0 + row) * 2304 + ch * 8);
    *(uint4*)&Qs[row * 72 + ch * 8] = v;
  }
  // ---- stage K: 128 rows (clamped at s_global<0; masked later)
  #pragma unroll
  for (int r = 0; r < 4; r++){
    int idx = tid + r * 256;
    int row = idx >> 3, ch = idx & 7;
    int sg = t0 - 64 + row; sg = sg < 0 ? 0 : sg;
    uint4 v = *(const uint4*)(qbase + 768 + (size_t)sg * 2304 + ch * 8);
    *(uint4*)&Ks[row * 72 + ch * 8] = v;
  }
  // ---- stage V transposed (s-major lane assignment -> 2-way LDS writes)
  #pragma unroll
  for (int r = 0; r < 4; r++){
    int idx = tid + r * 256;
    int s = idx & 127, ch = idx >> 7;
    int sg = t0 - 64 + s; sg = sg < 0 ? 0 : sg;
    uint4 v = *(const uint4*)(qbase + 1536 + (size_t)sg * 2304 + ch * 8);
    unsigned short tmp[8];
    *(uint4*)tmp = v;
    #pragma unroll
    for (int j = 0; j < 8; j++)
      Vt[(ch * 8 + j) * 136 + s] = tmp[j];
  }
  __syncthreads();

  // ---- S = Q K^T for 16 own rows x 128 cols (8 col-fragments x 2 k-steps)
  f32x4 sc[8];
  #pragma unroll
  for (int sj = 0; sj < 8; sj++) sc[sj] = (f32x4){0.f, 0.f, 0.f, 0.f};
  #pragma unroll
  for (int kk = 0; kk < 2; kk++){
    bf16x8 aq = *(const bf16x8*)&Qs[(wid * 16 + la) * 72 + kk * 32 + hi * 8];
    #pragma unroll
    for (int sj = 0; sj < 8; sj++){
      bf16x8 bk = *(const bf16x8*)&Ks[(sj * 16 + la) * 72 + kk * 32 + hi * 8];
      sc[sj] = __builtin_amdgcn_mfma_f32_16x16x32_bf16(aq, bk, sc[sj], 0, 0, 0);
    }
  }

  // ---- masked in-register softmax (row = wid*16 + hi*4 + r2, col = sj*16 + la)
  float inv[4];
  #pragma unroll
  for (int r2 = 0; r2 < 4; r2++){
    int row = wid * 16 + hi * 4 + r2;
    float mx = -1e30f;
    #pragma unroll
    for (int sj = 0; sj < 8; sj++){
      int sl = sj * 16 + la;
      bool valid = (sl >= row + 1) && (sl <= row + 64) && (t0 - 64 + sl >= 0);
      float sv = valid ? sc[sj][r2] * 0.125f : -1e30f;
      sc[sj][r2] = sv;
      mx = fmaxf(mx, sv);
    }
    #pragma unroll
    for (int o = 8; o >= 1; o >>= 1) mx = fmaxf(mx, __shfl_xor(mx, o));
    float sum = 0.0f;
    #pragma unroll
    for (int sj = 0; sj < 8; sj++){
      float p = __expf(sc[sj][r2] - mx);
      sc[sj][r2] = p;
      sum += p;
    }
    #pragma unroll
    for (int o = 8; o >= 1; o >>= 1) sum += __shfl_xor(sum, o);
    inv[r2] = 1.0f / sum;
  }

  // ---- P -> LDS (bf16), per-wave region
  unsigned short* myP = Ps[wid];
  #pragma unroll
  for (int sj = 0; sj < 8; sj++)
    #pragma unroll
    for (int r2 = 0; r2 < 4; r2++)
      myP[(hi * 4 + r2) * 136 + sj * 16 + la] = f2b(sc[sj][r2]);

  __syncthreads();

  // ---- O = P V  (A = P[16x128], B^T = Vt[64x128], 4 n-frags x 4 k-steps)
  f32x4 oacc[4];
  #pragma unroll
  for (int nj = 0; nj < 4; nj++) oacc[nj] = (f32x4){0.f, 0.f, 0.f, 0.f};
  #pragma unroll
  for (int ks = 0; ks < 4; ks++){
    bf16x8 ap = *(const bf16x8*)&myP[la * 136 + ks * 32 + hi * 8];
    #pragma unroll
    for (int nj = 0; nj < 4; nj++){
      bf16x8 bv = *(const bf16x8*)&Vt[(nj * 16 + la) * 136 + ks * 32 + hi * 8];
      oacc[nj] = __builtin_amdgcn_mfma_f32_16x16x32_bf16(ap, bv, oacc[nj], 0, 0, 0);
    }
  }

  // ---- write O (bf16, head-concat layout), scaled by 1/rowsum
  unsigned short* obase = attn + (size_t)(b * 1024 + t0) * 768 + h * 64;
  #pragma unroll
  for (int nj = 0; nj < 4; nj++)
    #pragma unroll
    for (int r2 = 0; r2 < 4; r2++){
      int row = wid * 16 + hi * 4 + r2;
      obase[(size_t)row * 768 + nj * 16 + la] = f2b(oacc[nj][r2] * inv[r2]);
    }
}

__global__ void aux_k(float* p){ if (threadIdx.x == 0) p[0] = 0.0f; }

// ----------------------------------------------------------------------------------
extern "C" void kernel_launch(void* const* d_in, const int* in_sizes, int n_in,
                              void* d_out, int out_size, void* d_ws, size_t ws_size,
                              hipStream_t stream)
{
  const float* x      = (const float*)d_in[0];
  const float* w_q    = (const float*)d_in[1];
  const float* w_k    = (const float*)d_in[2];
  const float* w_v    = (const float*)d_in[3];
  const float* w_proj = (const float*)d_in[4];
  const float* b_proj = (const float*)d_in[5];
  const float* w_ff1  = (const float*)d_in[6];
  const float* b_ff1  = (const float*)d_in[7];
  const float* w_ff2  = (const float*)d_in[8];
  const float* b_ff2  = (const float*)d_in[9];
  const float* g1     = (const float*)d_in[10];
  const float* g2     = (const float*)d_in[11];
  float* out = (float*)d_out;

  char* ws = (char*)d_ws;
  size_t off = 0;
  auto alloc = [&](size_t bytes){ size_t r = off; off += (bytes + 255) & ~(size_t)255; return r; };
  const size_t BT = 8 * 1024;  // 8192 rows

  unsigned short* h     = (unsigned short*)(ws + alloc(BT * 768 * 2));   // reused for attn out
  unsigned short* qkv   = (unsigned short*)(ws + alloc(BT * 3072 * 2));  // reused for ffa
  float*          x2    = (float*)         (ws + alloc(BT * 768 * 4));
  unsigned short* h2    = (unsigned short*)(ws + alloc(BT * 768 * 2));
  unsigned short* WqkvT = (unsigned short*)(ws + alloc(2304 * 768 * 2));
  unsigned short* WprojT= (unsigned short*)(ws + alloc(768 * 768 * 2));
  unsigned short* Wff1T = (unsigned short*)(ws + alloc(3072 * 768 * 2));
  unsigned short* Wff2T = (unsigned short*)(ws + alloc(768 * 3072 * 2));
  unsigned short* attn  = h;     // h dead after QKV GEMM
  unsigned short* ffa   = qkv;   // qkv dead after attention

  // all weights -> bf16 transposed, ONE launch
  transpose_all<<<6912, 256, 0, stream>>>(w_q, w_k, w_v, w_proj, w_ff1, w_ff2,
                                          WqkvT, WprojT, Wff1T, Wff2T);

  // h = rmsnorm(x, g1)
  rmsnorm_k<<<2048, 256, 0, stream>>>(x, g1, h);

  // qkv = h @ [Wq|Wk|Wv]   (M=8192, N=2304, K=768) — 2304 tiles, TPB=3
  gemm_db<3,false,false,false,false><<<768, 256, 0, stream>>>(h, WqkvT, nullptr, nullptr, qkv, 8192, 2304, 768);

  // sliding-window attention -> attn (bf16, [B*T][768] head-concat layout)
  attn_k<<<8 * 12 * 16, 256, 0, stream>>>(qkv, attn);

  // x2 = x + attn @ Wproj + b_proj   (fp32 out) — 768 tiles, TPB=1
  gemm_db<1,true,false,true,true><<<768, 256, 0, stream>>>(attn, WprojT, b_proj, x, x2, 8192, 768, 768);

  // h2 = rmsnorm(x2, g2)
  rmsnorm_k<<<2048, 256, 0, stream>>>(x2, g2, h2);

  // ffa = gelu(h2 @ Wff1 + b_ff1)   (M=8192, N=3072, K=768) — 3072 tiles, TPB=4
  gemm_db<4,true,true,false,false><<<768, 256, 0, stream>>>(h2, Wff1T, b_ff1, nullptr, ffa, 8192, 3072, 768);

  // out = x2 + ffa @ Wff2 + b_ff2   (M=8192, N=768, K=3072) — 768 tiles, TPB=1
  gemm_db<1,true,false,true,true><<<768, 256, 0, stream>>>(ffa, Wff2T, b_ff2, x2, out, 8192, 768, 3072);

  // aux scalar
  aux_k<<<1, 64, 0, stream>>>(out + 6291456);
}

// Round 14
// 204.314 us; speedup vs baseline: 1.2060x; 1.0049x over previous
//
#include <hip/hip_runtime.h>
#include <cstdint>

#define DEVI __device__ __forceinline__

typedef __bf16 bf16x8 __attribute__((ext_vector_type(8)));
typedef float  f32x4  __attribute__((ext_vector_type(4)));

template<int V> struct IC { static constexpr int v = V; };

DEVI unsigned short f2b(float f){
  unsigned u = __builtin_bit_cast(unsigned, f);
  unsigned r = u + 0x7FFF + ((u >> 16) & 1);
  return (unsigned short)(r >> 16);
}
DEVI float b2f(unsigned short s){
  unsigned u = ((unsigned)s) << 16;
  return __builtin_bit_cast(float, u);
}
DEVI float gelu_f(float x){
  float u = 0.7978845608028654f * (x + 0.044715f * x * x * x);
  float e = __expf(2.0f * u);
  return x * (1.0f - 1.0f / (e + 1.0f));   // == 0.5x(1+tanh(u)), safe at e->inf / e->0
}
DEVI void gl_lds16(const unsigned short* g, unsigned short* l){
  __builtin_amdgcn_global_load_lds(
      (const __attribute__((address_space(1))) unsigned int*)g,
      (__attribute__((address_space(3))) unsigned int*)l, 16, 0, 0);
}

// ---------------- fused weight transpose + f32->bf16 (ONE launch for all 6) -------
__global__ __launch_bounds__(256)
void transpose_all(const float* __restrict__ w_q, const float* __restrict__ w_k,
                   const float* __restrict__ w_v, const float* __restrict__ w_proj,
                   const float* __restrict__ w_ff1, const float* __restrict__ w_ff2,
                   unsigned short* __restrict__ WqkvT, unsigned short* __restrict__ WprojT,
                   unsigned short* __restrict__ Wff1T, unsigned short* __restrict__ Wff2T)
{
  __shared__ float tile[32][33];
  int blk = blockIdx.x;
  const float* in; unsigned short* out; int R, C, b0;
  if      (blk < 576) { in = w_q;    out = WqkvT;              R = 768;  C = 768;  b0 = 0;    }
  else if (blk < 1152){ in = w_k;    out = WqkvT + 768 * 768;  R = 768;  C = 768;  b0 = 576;  }
  else if (blk < 1728){ in = w_v;    out = WqkvT + 1536 * 768; R = 768;  C = 768;  b0 = 1152; }
  else if (blk < 2304){ in = w_proj; out = WprojT;             R = 768;  C = 768;  b0 = 1728; }
  else if (blk < 4608){ in = w_ff1;  out = Wff1T;              R = 768;  C = 3072; b0 = 2304; }
  else                { in = w_ff2;  out = Wff2T;              R = 3072; C = 768;  b0 = 4608; }
  int lb = blk - b0;
  int nbx = C >> 5;
  int bx = lb % nbx, by = lb / nbx;
  int c0 = bx << 5, r0 = by << 5;
  int tx = threadIdx.x & 31, ty = threadIdx.x >> 5;   // 32 x 8
  #pragma unroll
  for (int j = 0; j < 32; j += 8)
    tile[ty + j][tx] = in[(size_t)(r0 + ty + j) * C + c0 + tx];
  __syncthreads();
  #pragma unroll
  for (int j = 0; j < 32; j += 8)
    out[(size_t)(c0 + ty + j) * R + r0 + tx] = f2b(tile[tx][ty + j]);
}

// ---------------- RMSNorm: x f32 [rows][768] -> out bf16, 1 wave per row ----------
__global__ __launch_bounds__(256)
void rmsnorm_k(const float* __restrict__ x, const float* __restrict__ g,
               unsigned short* __restrict__ out)
{
  int wid = threadIdx.x >> 6, lane = threadIdx.x & 63;
  size_t row = (size_t)blockIdx.x * 4 + wid;
  const float* xr = x + row * 768;
  float4 v[3];
  float ss = 0.0f;
  #pragma unroll
  for (int c = 0; c < 3; c++){
    v[c] = *(const float4*)&xr[lane * 4 + c * 256];
    ss += v[c].x * v[c].x + v[c].y * v[c].y + v[c].z * v[c].z + v[c].w * v[c].w;
  }
  #pragma unroll
  for (int o = 32; o >= 1; o >>= 1) ss += __shfl_xor(ss, o);
  float rs = rsqrtf(ss * (1.0f / 768.0f) + 1e-6f);
  #pragma unroll
  for (int c = 0; c < 3; c++){
    const float4 gv = *(const float4*)&g[lane * 4 + c * 256];
    ushort4 o4;
    o4.x = f2b(v[c].x * rs * gv.x);
    o4.y = f2b(v[c].y * rs * gv.y);
    o4.z = f2b(v[c].z * rs * gv.z);
    o4.w = f2b(v[c].w * rs * gv.w);
    *(ushort4*)&out[row * 768 + lane * 4 + c * 256] = o4;
  }
}

// ---------------- GEMM BMx128 PERSISTENT, ONE-barrier-per-tile pipeline -----------
// r13 schedule, templated tile height:
//   BM=64 : 4 waves 2x2, per-wave 32x64 (MI=2), 48KB LDS, 3 blocks/CU — best for
//           long-K / N=768 shapes (fill-perfect grids).
//   BM=128: 4 waves 2x2, per-wave 64x64 (MI=4), 64KB LDS, 2 blocks/CU — 0.50
//           KB-LDS/MFMA vs 0.75 at BM=64: raises the LDS-BW-bound MfmaUtil
//           ceiling ~28%->~41% (r13 measured: LDS traffic model matches 917
//           cy/step within 8%). Used where the grid divides 512 exactly.
// Pipeline per K-tile t: vmcnt(0) [drains stage(t), issued one full tile ago] ->
// barrier -> sched_barrier -> stage(t+1) -> ds_reads -> MFMA. One barrier/tile.
// Race ledger as r13. Requires M%BM==0, N%128==0, K%128==0, grid%8==0,
// grid*TPB == total tiles.
template<int BM, int TPB, bool BIAS, bool GELU_, bool RES, bool OUTF32>
__global__ __launch_bounds__(256, BM == 64 ? 3 : 2)
void gemm_db(const unsigned short* __restrict__ A, const unsigned short* __restrict__ Bt,
             const float* __restrict__ bias, const float* __restrict__ res,
             void* __restrict__ outp, int M, int N, int K)
{
  constexpr int MI = BM / 32;             // m-frags per wave
  constexpr int AL = BM / 32;             // A-stage instrs per wave
  constexpr int BUFSZ = (BM + 128) * 64;  // shorts per buffer
  __shared__ unsigned short sm[2][BUFSZ];

  int tid = threadIdx.x, wid = tid >> 6, lane = tid & 63;
  int la = lane & 15, hi = lane >> 4;
  int wm = wid >> 1, wn = wid & 1;        // 2x2 waves
  int tiles_n = N >> 7;
  int bid = blockIdx.x;
  bid = (bid & 7) * (gridDim.x >> 3) + (bid >> 3);   // XCD-aware swizzle
  int g0 = bid * TPB;                     // consecutive tiles: same A-stripe (L2 reuse)
  int NT = K >> 6;

  size_t constA[AL]; unsigned short* aDst[2][AL];
  size_t constB[4];  unsigned short* bDst[2][4];
  #pragma unroll
  for (int l = 0; l < AL; l++){
    int cb = wid * (BM * 2) + l * 64;
    int idx = cb + lane;
    int row = idx >> 3, sl2 = (idx & 7) ^ (row & 7);
    constA[l] = (size_t)row * K + sl2 * 8;
    aDst[0][l] = &sm[0][cb * 8];
    aDst[1][l] = &sm[1][cb * 8];
  }
  #pragma unroll
  for (int l = 0; l < 4; l++){
    int cb = wid * 256 + l * 64;
    int idx = cb + lane;
    int row = idx >> 3, sl2 = (idx & 7) ^ (row & 7);
    constB[l] = (size_t)row * K + sl2 * 8;
    bDst[0][l] = &sm[0][BM * 64 + cb * 8];
    bDst[1][l] = &sm[1][BM * 64 + cb * 8];
  }

  const unsigned short* fa[2][2];
  const unsigned short* fb[2][2];
  #pragma unroll
  for (int bf = 0; bf < 2; bf++)
    #pragma unroll
    for (int kk = 0; kk < 2; kk++){
      int sw = (((kk * 4 + hi) ^ (la & 7))) * 8;
      fa[bf][kk] = &sm[bf][(wm * (BM / 2) + la) * 64 + sw];
      fb[bf][kk] = &sm[bf][BM * 64 + (wn * 64 + la) * 64 + sw];
    }

  const unsigned short* aSrc[AL];
  const unsigned short* bSrc[4];
  auto setSrc = [&](int g){
    int m0 = (g / tiles_n) * BM, n0 = (g % tiles_n) << 7;
    #pragma unroll
    for (int l = 0; l < AL; l++) aSrc[l] = A  + (size_t)m0 * K + constA[l];
    #pragma unroll
    for (int l = 0; l < 4;  l++) bSrc[l] = Bt + (size_t)n0 * K + constB[l];
  };
  auto stageTo = [&](auto BF){
    constexpr int bf = decltype(BF)::v;
    #pragma unroll
    for (int l = 0; l < AL; l++){ gl_lds16(aSrc[l], aDst[bf][l]); aSrc[l] += 64; }
    #pragma unroll
    for (int l = 0; l < 4; l++){ gl_lds16(bSrc[l], bDst[bf][l]); bSrc[l] += 64; }
  };

  setSrc(g0);
  stageTo(IC<0>{});                       // ONE cold start per block

  float* outF = (float*)outp;
  unsigned short* outB = (unsigned short*)outp;

  for (int ot = 0; ot < TPB; ot++){
    int g = g0 + ot;
    int m0 = (g / tiles_n) * BM, n0 = (g % tiles_n) << 7;

    f32x4 acc[MI][4] = {};

    auto tile_step = [&](auto BUF, int t){
      constexpr int CB = decltype(BUF)::v;
      // drain stage(t) — issued one full tile ago (cold only at block start)
      asm volatile("s_waitcnt vmcnt(0)" ::: "memory");
      __builtin_amdgcn_s_barrier();                     // buf[CB] visible; buf[CB^1]
      __builtin_amdgcn_sched_barrier(0);                //   readers all done
      if (t + 1 < NT || ot + 1 < TPB){
        if (t + 1 == NT) setSrc(g + 1);                 // cross into next tile's K=0
        stageTo(IC<CB ^ 1>{});
      }

      bf16x8 afr[MI][2], bfr[4][2];
      #pragma unroll
      for (int mm = 0; mm < MI; mm++){
        afr[mm][0] = *(const bf16x8*)(fa[CB][0] + mm * 1024);
        afr[mm][1] = *(const bf16x8*)(fa[CB][1] + mm * 1024);
      }
      #pragma unroll
      for (int nn = 0; nn < 4; nn++){
        bfr[nn][0] = *(const bf16x8*)(fb[CB][0] + nn * 1024);
        bfr[nn][1] = *(const bf16x8*)(fb[CB][1] + nn * 1024);
      }
      __builtin_amdgcn_s_setprio(1);
      #pragma unroll
      for (int mm = 0; mm < MI; mm++)
        #pragma unroll
        for (int nn = 0; nn < 4; nn++)
          #pragma unroll
          for (int kk = 0; kk < 2; kk++)
            acc[mm][nn] = __builtin_amdgcn_mfma_f32_16x16x32_bf16(
                afr[mm][kk], bfr[nn][kk], acc[mm][nn], 0, 0, 0);
      __builtin_amdgcn_s_setprio(0);
      // no end-of-tile barrier: next tile's vmcnt(0)+barrier provides the fence
    };

    for (int t = 0; t < NT; t += 2){                    // NT even (K%128==0)
      tile_step(IC<0>{}, t);
      tile_step(IC<1>{}, t + 1);
    }

    // ---- epilogue for tile g (stores drain at next tile's vmcnt(0))
    #pragma unroll
    for (int mm = 0; mm < MI; mm++){
      int rowb = m0 + wm * (BM / 2) + mm * 16 + hi * 4;
      #pragma unroll
      for (int nn = 0; nn < 4; nn++){
        int col = n0 + wn * 64 + nn * 16 + la;
        float bv = BIAS ? bias[col] : 0.0f;
        #pragma unroll
        for (int r = 0; r < 4; r++){
          float val = acc[mm][nn][r] + bv;
          if (GELU_) val = gelu_f(val);
          if (RES)   val += res[(size_t)(rowb + r) * N + col];
          size_t o = (size_t)(rowb + r) * N + col;
          if (OUTF32) outF[o] = val;
          else        outB[o] = f2b(val);
        }
      }
    }
  }
}

// ---------------- sliding-window causal attention, W=64, D=64, MFMA tile ----------
__global__ __launch_bounds__(256)
void attn_k(const unsigned short* __restrict__ qkv, unsigned short* __restrict__ attn)
{
  __shared__ unsigned short Qs[64 * 72];       // stride 72: b128 reads at 8-way min
  __shared__ unsigned short Ks[128 * 72];
  __shared__ unsigned short Vt[64 * 136];      // V^T [d][s], stride 136
  __shared__ unsigned short Ps[4][16 * 136];   // per-wave P rows

  int tid = threadIdx.x, wid = tid >> 6, lane = tid & 63;
  int la = lane & 15, hi = lane >> 4;
  int blk = blockIdx.x;
  blk = (blk & 7) * (gridDim.x >> 3) + (blk >> 3);   // XCD swizzle (1536 % 8 == 0)
  int tile = blk & 15, hb = blk >> 4;
  int h = hb % 12, b = hb / 12;
  int t0 = tile << 6;

  const unsigned short* qbase = qkv + (size_t)(b * 1024) * 2304 + h * 64;

  // ---- stage Q: 64 rows x 8 chunks of 8 bf16
  #pragma unroll
  for (int r = 0; r < 2; r++){
    int idx = tid + r * 256;
    int row = idx >> 3, ch = idx & 7;
    uint4 v = *(const uint4*)(qbase + (size_t)(t0 + row) * 2304 + ch * 8);
    *(uint4*)&Qs[row * 72 + ch * 8] = v;
  }
  // ---- stage K: 128 rows (clamped at s_global<0; masked later)
  #pragma unroll
  for (int r = 0; r < 4; r++){
    int idx = tid + r * 256;
    int row = idx >> 3, ch = idx & 7;
    int sg = t0 - 64 + row; sg = sg < 0 ? 0 : sg;
    uint4 v = *(const uint4*)(qbase + 768 + (size_t)sg * 2304 + ch * 8);
    *(uint4*)&Ks[row * 72 + ch * 8] = v;
  }
  // ---- stage V transposed (s-major lane assignment -> 2-way LDS writes)
  #pragma unroll
  for (int r = 0; r < 4; r++){
    int idx = tid + r * 256;
    int s = idx & 127, ch = idx >> 7;
    int sg = t0 - 64 + s; sg = sg < 0 ? 0 : sg;
    uint4 v = *(const uint4*)(qbase + 1536 + (size_t)sg * 2304 + ch * 8);
    unsigned short tmp[8];
    *(uint4*)tmp = v;
    #pragma unroll
    for (int j = 0; j < 8; j++)
      Vt[(ch * 8 + j) * 136 + s] = tmp[j];
  }
  __syncthreads();

  // ---- S = Q K^T for 16 own rows x 128 cols (8 col-fragments x 2 k-steps)
  f32x4 sc[8];
  #pragma unroll
  for (int sj = 0; sj < 8; sj++) sc[sj] = (f32x4){0.f, 0.f, 0.f, 0.f};
  #pragma unroll
  for (int kk = 0; kk < 2; kk++){
    bf16x8 aq = *(const bf16x8*)&Qs[(wid * 16 + la) * 72 + kk * 32 + hi * 8];
    #pragma unroll
    for (int sj = 0; sj < 8; sj++){
      bf16x8 bk = *(const bf16x8*)&Ks[(sj * 16 + la) * 72 + kk * 32 + hi * 8];
      sc[sj] = __builtin_amdgcn_mfma_f32_16x16x32_bf16(aq, bk, sc[sj], 0, 0, 0);
    }
  }

  // ---- masked in-register softmax (row = wid*16 + hi*4 + r2, col = sj*16 + la)
  float inv[4];
  #pragma unroll
  for (int r2 = 0; r2 < 4; r2++){
    int row = wid * 16 + hi * 4 + r2;
    float mx = -1e30f;
    #pragma unroll
    for (int sj = 0; sj < 8; sj++){
      int sl = sj * 16 + la;
      bool valid = (sl >= row + 1) && (sl <= row + 64) && (t0 - 64 + sl >= 0);
      float sv = valid ? sc[sj][r2] * 0.125f : -1e30f;
      sc[sj][r2] = sv;
      mx = fmaxf(mx, sv);
    }
    #pragma unroll
    for (int o = 8; o >= 1; o >>= 1) mx = fmaxf(mx, __shfl_xor(mx, o));
    float sum = 0.0f;
    #pragma unroll
    for (int sj = 0; sj < 8; sj++){
      float p = __expf(sc[sj][r2] - mx);
      sc[sj][r2] = p;
      sum += p;
    }
    #pragma unroll
    for (int o = 8; o >= 1; o >>= 1) sum += __shfl_xor(sum, o);
    inv[r2] = 1.0f / sum;
  }

  // ---- P -> LDS (bf16), per-wave region
  unsigned short* myP = Ps[wid];
  #pragma unroll
  for (int sj = 0; sj < 8; sj++)
    #pragma unroll
    for (int r2 = 0; r2 < 4; r2++)
      myP[(hi * 4 + r2) * 136 + sj * 16 + la] = f2b(sc[sj][r2]);

  __syncthreads();

  // ---- O = P V  (A = P[16x128], B^T = Vt[64x128], 4 n-frags x 4 k-steps)
  f32x4 oacc[4];
  #pragma unroll
  for (int nj = 0; nj < 4; nj++) oacc[nj] = (f32x4){0.f, 0.f, 0.f, 0.f};
  #pragma unroll
  for (int ks = 0; ks < 4; ks++){
    bf16x8 ap = *(const bf16x8*)&myP[la * 136 + ks * 32 + hi * 8];
    #pragma unroll
    for (int nj = 0; nj < 4; nj++){
      bf16x8 bv = *(const bf16x8*)&Vt[(nj * 16 + la) * 136 + ks * 32 + hi * 8];
      oacc[nj] = __builtin_amdgcn_mfma_f32_16x16x32_bf16(ap, bv, oacc[nj], 0, 0, 0);
    }
  }

  // ---- write O (bf16, head-concat layout), scaled by 1/rowsum
  unsigned short* obase = attn + (size_t)(b * 1024 + t0) * 768 + h * 64;
  #pragma unroll
  for (int nj = 0; nj < 4; nj++)
    #pragma unroll
    for (int r2 = 0; r2 < 4; r2++){
      int row = wid * 16 + hi * 4 + r2;
      obase[(size_t)row * 768 + nj * 16 + la] = f2b(oacc[nj][r2] * inv[r2]);
    }
}

__global__ void aux_k(float* p){ if (threadIdx.x == 0) p[0] = 0.0f; }

// ----------------------------------------------------------------------------------
extern "C" void kernel_launch(void* const* d_in, const int* in_sizes, int n_in,
                              void* d_out, int out_size, void* d_ws, size_t ws_size,
                              hipStream_t stream)
{
  const float* x      = (const float*)d_in[0];
  const float* w_q    = (const float*)d_in[1];
  const float* w_k    = (const float*)d_in[2];
  const float* w_v    = (const float*)d_in[3];
  const float* w_proj = (const float*)d_in[4];
  const float* b_proj = (const float*)d_in[5];
  const float* w_ff1  = (const float*)d_in[6];
  const float* b_ff1  = (const float*)d_in[7];
  const float* w_ff2  = (const float*)d_in[8];
  const float* b_ff2  = (const float*)d_in[9];
  const float* g1     = (const float*)d_in[10];
  const float* g2     = (const float*)d_in[11];
  float* out = (float*)d_out;

  char* ws = (char*)d_ws;
  size_t off = 0;
  auto alloc = [&](size_t bytes){ size_t r = off; off += (bytes + 255) & ~(size_t)255; return r; };
  const size_t BT = 8 * 1024;  // 8192 rows

  unsigned short* h     = (unsigned short*)(ws + alloc(BT * 768 * 2));   // reused for attn out
  unsigned short* qkv   = (unsigned short*)(ws + alloc(BT * 3072 * 2));  // reused for ffa
  float*          x2    = (float*)         (ws + alloc(BT * 768 * 4));
  unsigned short* h2    = (unsigned short*)(ws + alloc(BT * 768 * 2));
  unsigned short* WqkvT = (unsigned short*)(ws + alloc(2304 * 768 * 2));
  unsigned short* WprojT= (unsigned short*)(ws + alloc(768 * 768 * 2));
  unsigned short* Wff1T = (unsigned short*)(ws + alloc(3072 * 768 * 2));
  unsigned short* Wff2T = (unsigned short*)(ws + alloc(768 * 3072 * 2));
  unsigned short* attn  = h;     // h dead after QKV GEMM
  unsigned short* ffa   = qkv;   // qkv dead after attention

  // all weights -> bf16 transposed, ONE launch
  transpose_all<<<6912, 256, 0, stream>>>(w_q, w_k, w_v, w_proj, w_ff1, w_ff2,
                                          WqkvT, WprojT, Wff1T, Wff2T);

  // h = rmsnorm(x, g1)
  rmsnorm_k<<<2048, 256, 0, stream>>>(x, g1, h);

  // qkv = h @ [Wq|Wk|Wv]   (M=8192, N=2304, K=768) — BM=64, 2304 tiles, TPB=3
  gemm_db<64,3,false,false,false,false><<<768, 256, 0, stream>>>(h, WqkvT, nullptr, nullptr, qkv, 8192, 2304, 768);

  // sliding-window attention -> attn (bf16, [B*T][768] head-concat layout)
  attn_k<<<8 * 12 * 16, 256, 0, stream>>>(qkv, attn);

  // x2 = x + attn @ Wproj + b_proj   (fp32 out) — BM=64, 768 tiles, TPB=1
  gemm_db<64,1,true,false,true,true><<<768, 256, 0, stream>>>(attn, WprojT, b_proj, x, x2, 8192, 768, 768);

  // h2 = rmsnorm(x2, g2)
  rmsnorm_k<<<2048, 256, 0, stream>>>(x2, g2, h2);

  // ffa = gelu(h2 @ Wff1 + b_ff1)   (M=8192, N=3072, K=768) — BM=128 (64x64/wave,
  // 0.5 KB-LDS/MFMA), 1536 tiles, grid 512 = exact 2-blocks/CU round, TPB=3
  gemm_db<128,3,true,true,false,false><<<512, 256, 0, stream>>>(h2, Wff1T, b_ff1, nullptr, ffa, 8192, 3072, 768);

  // out = x2 + ffa @ Wff2 + b_ff2   (M=8192, N=768, K=3072) — BM=64, 768 tiles, TPB=1
  gemm_db<64,1,true,false,true,true><<<768, 256, 0, stream>>>(ffa, Wff2T, b_ff2, x2, out, 8192, 768, 3072);

  // aux scalar
  aux_k<<<1, 64, 0, stream>>>(out + 6291456);
}

// Round 15
// 200.526 us; speedup vs baseline: 1.2288x; 1.0189x over previous
//
#include <hip/hip_runtime.h>
#include <cstdint>

#define DEVI __device__ __forceinline__

typedef __bf16 bf16x8 __attribute__((ext_vector_type(8)));
typedef float  f32x4  __attribute__((ext_vector_type(4)));

template<int V> struct IC { static constexpr int v = V; };

DEVI unsigned short f2b(float f){
  unsigned u = __builtin_bit_cast(unsigned, f);
  unsigned r = u + 0x7FFF + ((u >> 16) & 1);
  return (unsigned short)(r >> 16);
}
DEVI float b2f(unsigned short s){
  unsigned u = ((unsigned)s) << 16;
  return __builtin_bit_cast(float, u);
}
DEVI float gelu_f(float x){
  float u = 0.7978845608028654f * (x + 0.044715f * x * x * x);
  float e = __expf(2.0f * u);
  return x * (1.0f - 1.0f / (e + 1.0f));   // == 0.5x(1+tanh(u)), safe at e->inf / e->0
}
DEVI void gl_lds16(const unsigned short* g, unsigned short* l){
  __builtin_amdgcn_global_load_lds(
      (const __attribute__((address_space(1))) unsigned int*)g,
      (__attribute__((address_space(3))) unsigned int*)l, 16, 0, 0);
}

// ---------------- fused weight transpose + f32->bf16 (ONE launch for all 6) -------
__global__ __launch_bounds__(256)
void transpose_all(const float* __restrict__ w_q, const float* __restrict__ w_k,
                   const float* __restrict__ w_v, const float* __restrict__ w_proj,
                   const float* __restrict__ w_ff1, const float* __restrict__ w_ff2,
                   unsigned short* __restrict__ WqkvT, unsigned short* __restrict__ WprojT,
                   unsigned short* __restrict__ Wff1T, unsigned short* __restrict__ Wff2T)
{
  __shared__ float tile[32][33];
  int blk = blockIdx.x;
  const float* in; unsigned short* out; int R, C, b0;
  if      (blk < 576) { in = w_q;    out = WqkvT;              R = 768;  C = 768;  b0 = 0;    }
  else if (blk < 1152){ in = w_k;    out = WqkvT + 768 * 768;  R = 768;  C = 768;  b0 = 576;  }
  else if (blk < 1728){ in = w_v;    out = WqkvT + 1536 * 768; R = 768;  C = 768;  b0 = 1152; }
  else if (blk < 2304){ in = w_proj; out = WprojT;             R = 768;  C = 768;  b0 = 1728; }
  else if (blk < 4608){ in = w_ff1;  out = Wff1T;              R = 768;  C = 3072; b0 = 2304; }
  else                { in = w_ff2;  out = Wff2T;              R = 3072; C = 768;  b0 = 4608; }
  int lb = blk - b0;
  int nbx = C >> 5;
  int bx = lb % nbx, by = lb / nbx;
  int c0 = bx << 5, r0 = by << 5;
  int tx = threadIdx.x & 31, ty = threadIdx.x >> 5;   // 32 x 8
  #pragma unroll
  for (int j = 0; j < 32; j += 8)
    tile[ty + j][tx] = in[(size_t)(r0 + ty + j) * C + c0 + tx];
  __syncthreads();
  #pragma unroll
  for (int j = 0; j < 32; j += 8)
    out[(size_t)(c0 + ty + j) * R + r0 + tx] = f2b(tile[tx][ty + j]);
}

// ---------------- RMSNorm: [rows][768] f32-or-bf16 -> out bf16, 1 wave per row ----
template<bool INF32>
__global__ __launch_bounds__(256)
void rmsnorm_k(const void* __restrict__ xin, const float* __restrict__ g,
               unsigned short* __restrict__ out)
{
  int wid = threadIdx.x >> 6, lane = threadIdx.x & 63;
  size_t row = (size_t)blockIdx.x * 4 + wid;
  float v[12];
  float ss = 0.0f;
  if (INF32){
    const float* xr = (const float*)xin + row * 768;
    #pragma unroll
    for (int c = 0; c < 3; c++){
      float4 t = *(const float4*)&xr[lane * 4 + c * 256];
      v[c * 4 + 0] = t.x; v[c * 4 + 1] = t.y; v[c * 4 + 2] = t.z; v[c * 4 + 3] = t.w;
    }
  } else {
    const unsigned short* xr = (const unsigned short*)xin + row * 768;
    #pragma unroll
    for (int c = 0; c < 3; c++){
      ushort4 t = *(const ushort4*)&xr[lane * 4 + c * 256];
      v[c * 4 + 0] = b2f(t.x); v[c * 4 + 1] = b2f(t.y);
      v[c * 4 + 2] = b2f(t.z); v[c * 4 + 3] = b2f(t.w);
    }
  }
  #pragma unroll
  for (int j = 0; j < 12; j++) ss += v[j] * v[j];
  #pragma unroll
  for (int o = 32; o >= 1; o >>= 1) ss += __shfl_xor(ss, o);
  float rs = rsqrtf(ss * (1.0f / 768.0f) + 1e-6f);
  #pragma unroll
  for (int c = 0; c < 3; c++){
    const float4 gv = *(const float4*)&g[lane * 4 + c * 256];
    ushort4 o4;
    o4.x = f2b(v[c * 4 + 0] * rs * gv.x);
    o4.y = f2b(v[c * 4 + 1] * rs * gv.y);
    o4.z = f2b(v[c * 4 + 2] * rs * gv.z);
    o4.w = f2b(v[c * 4 + 3] * rs * gv.w);
    *(ushort4*)&out[row * 768 + lane * 4 + c * 256] = o4;
  }
}

// ---------------- GEMM BMx128 PERSISTENT, ONE-barrier-per-tile pipeline -----------
// r14 schedule unchanged. RESM: 0 = no residual, 1 = f32 residual, 2 = bf16.
// Requires M%BM==0, N%128==0, K%128==0, grid%8==0, grid*TPB == total tiles.
template<int BM, int TPB, bool BIAS, bool GELU_, int RESM, bool OUTF32>
__global__ __launch_bounds__(256, BM == 64 ? 3 : 2)
void gemm_db(const unsigned short* __restrict__ A, const unsigned short* __restrict__ Bt,
             const float* __restrict__ bias, const void* __restrict__ res,
             void* __restrict__ outp, int M, int N, int K)
{
  constexpr int MI = BM / 32;             // m-frags per wave
  constexpr int AL = BM / 32;             // A-stage instrs per wave
  constexpr int BUFSZ = (BM + 128) * 64;  // shorts per buffer
  __shared__ unsigned short sm[2][BUFSZ];

  int tid = threadIdx.x, wid = tid >> 6, lane = tid & 63;
  int la = lane & 15, hi = lane >> 4;
  int wm = wid >> 1, wn = wid & 1;        // 2x2 waves
  int tiles_n = N >> 7;
  int bid = blockIdx.x;
  bid = (bid & 7) * (gridDim.x >> 3) + (bid >> 3);   // XCD-aware swizzle
  int g0 = bid * TPB;                     // consecutive tiles: same A-stripe (L2 reuse)
  int NT = K >> 6;

  size_t constA[AL]; unsigned short* aDst[2][AL];
  size_t constB[4];  unsigned short* bDst[2][4];
  #pragma unroll
  for (int l = 0; l < AL; l++){
    int cb = wid * (BM * 2) + l * 64;
    int idx = cb + lane;
    int row = idx >> 3, sl2 = (idx & 7) ^ (row & 7);
    constA[l] = (size_t)row * K + sl2 * 8;
    aDst[0][l] = &sm[0][cb * 8];
    aDst[1][l] = &sm[1][cb * 8];
  }
  #pragma unroll
  for (int l = 0; l < 4; l++){
    int cb = wid * 256 + l * 64;
    int idx = cb + lane;
    int row = idx >> 3, sl2 = (idx & 7) ^ (row & 7);
    constB[l] = (size_t)row * K + sl2 * 8;
    bDst[0][l] = &sm[0][BM * 64 + cb * 8];
    bDst[1][l] = &sm[1][BM * 64 + cb * 8];
  }

  const unsigned short* fa[2][2];
  const unsigned short* fb[2][2];
  #pragma unroll
  for (int bf = 0; bf < 2; bf++)
    #pragma unroll
    for (int kk = 0; kk < 2; kk++){
      int sw = (((kk * 4 + hi) ^ (la & 7))) * 8;
      fa[bf][kk] = &sm[bf][(wm * (BM / 2) + la) * 64 + sw];
      fb[bf][kk] = &sm[bf][BM * 64 + (wn * 64 + la) * 64 + sw];
    }

  const unsigned short* aSrc[AL];
  const unsigned short* bSrc[4];
  auto setSrc = [&](int g){
    int m0 = (g / tiles_n) * BM, n0 = (g % tiles_n) << 7;
    #pragma unroll
    for (int l = 0; l < AL; l++) aSrc[l] = A  + (size_t)m0 * K + constA[l];
    #pragma unroll
    for (int l = 0; l < 4;  l++) bSrc[l] = Bt + (size_t)n0 * K + constB[l];
  };
  auto stageTo = [&](auto BF){
    constexpr int bf = decltype(BF)::v;
    #pragma unroll
    for (int l = 0; l < AL; l++){ gl_lds16(aSrc[l], aDst[bf][l]); aSrc[l] += 64; }
    #pragma unroll
    for (int l = 0; l < 4; l++){ gl_lds16(bSrc[l], bDst[bf][l]); bSrc[l] += 64; }
  };

  setSrc(g0);
  stageTo(IC<0>{});                       // ONE cold start per block

  float* outF = (float*)outp;
  unsigned short* outB = (unsigned short*)outp;
  const float* resF = (const float*)res;
  const unsigned short* resB = (const unsigned short*)res;

  for (int ot = 0; ot < TPB; ot++){
    int g = g0 + ot;
    int m0 = (g / tiles_n) * BM, n0 = (g % tiles_n) << 7;

    f32x4 acc[MI][4] = {};

    auto tile_step = [&](auto BUF, int t){
      constexpr int CB = decltype(BUF)::v;
      // drain stage(t) — issued one full tile ago (cold only at block start)
      asm volatile("s_waitcnt vmcnt(0)" ::: "memory");
      __builtin_amdgcn_s_barrier();                     // buf[CB] visible; buf[CB^1]
      __builtin_amdgcn_sched_barrier(0);                //   readers all done
      if (t + 1 < NT || ot + 1 < TPB){
        if (t + 1 == NT) setSrc(g + 1);                 // cross into next tile's K=0
        stageTo(IC<CB ^ 1>{});
      }

      bf16x8 afr[MI][2], bfr[4][2];
      #pragma unroll
      for (int mm = 0; mm < MI; mm++){
        afr[mm][0] = *(const bf16x8*)(fa[CB][0] + mm * 1024);
        afr[mm][1] = *(const bf16x8*)(fa[CB][1] + mm * 1024);
      }
      #pragma unroll
      for (int nn = 0; nn < 4; nn++){
        bfr[nn][0] = *(const bf16x8*)(fb[CB][0] + nn * 1024);
        bfr[nn][1] = *(const bf16x8*)(fb[CB][1] + nn * 1024);
      }
      __builtin_amdgcn_s_setprio(1);
      #pragma unroll
      for (int mm = 0; mm < MI; mm++)
        #pragma unroll
        for (int nn = 0; nn < 4; nn++)
          #pragma unroll
          for (int kk = 0; kk < 2; kk++)
            acc[mm][nn] = __builtin_amdgcn_mfma_f32_16x16x32_bf16(
                afr[mm][kk], bfr[nn][kk], acc[mm][nn], 0, 0, 0);
      __builtin_amdgcn_s_setprio(0);
      // no end-of-tile barrier: next tile's vmcnt(0)+barrier provides the fence
    };

    for (int t = 0; t < NT; t += 2){                    // NT even (K%128==0)
      tile_step(IC<0>{}, t);
      tile_step(IC<1>{}, t + 1);
    }

    // ---- epilogue for tile g (stores drain at next tile's vmcnt(0))
    #pragma unroll
    for (int mm = 0; mm < MI; mm++){
      int rowb = m0 + wm * (BM / 2) + mm * 16 + hi * 4;
      #pragma unroll
      for (int nn = 0; nn < 4; nn++){
        int col = n0 + wn * 64 + nn * 16 + la;
        float bv = BIAS ? bias[col] : 0.0f;
        #pragma unroll
        for (int r = 0; r < 4; r++){
          float val = acc[mm][nn][r] + bv;
          if (GELU_) val = gelu_f(val);
          size_t o = (size_t)(rowb + r) * N + col;
          if (RESM == 1) val += resF[o];
          if (RESM == 2) val += b2f(resB[o]);
          if (OUTF32) outF[o] = val;
          else        outB[o] = f2b(val);
        }
      }
    }
  }
}

// ---------------- sliding-window causal attention, W=64, D=64, MFMA tile ----------
__global__ __launch_bounds__(256)
void attn_k(const unsigned short* __restrict__ qkv, unsigned short* __restrict__ attn)
{
  __shared__ unsigned short Qs[64 * 72];       // stride 72: b128 reads at 8-way min
  __shared__ unsigned short Ks[128 * 72];
  __shared__ unsigned short Vt[64 * 136];      // V^T [d][s], stride 136
  __shared__ unsigned short Ps[4][16 * 136];   // per-wave P rows

  int tid = threadIdx.x, wid = tid >> 6, lane = tid & 63;
  int la = lane & 15, hi = lane >> 4;
  int blk = blockIdx.x;
  blk = (blk & 7) * (gridDim.x >> 3) + (blk >> 3);   // XCD swizzle (1536 % 8 == 0)
  int tile = blk & 15, hb = blk >> 4;
  int h = hb % 12, b = hb / 12;
  int t0 = tile << 6;

  const unsigned short* qbase = qkv + (size_t)(b * 1024) * 2304 + h * 64;

  // ---- stage Q: 64 rows x 8 chunks of 8 bf16
  #pragma unroll
  for (int r = 0; r < 2; r++){
    int idx = tid + r * 256;
    int row = idx >> 3, ch = idx & 7;
    uint4 v = *(const uint4*)(qbase + (size_t)(t0 + row) * 2304 + ch * 8);
    *(uint4*)&Qs[row * 72 + ch * 8] = v;
  }
  // ---- stage K: 128 rows (clamped at s_global<0; masked later)
  #pragma unroll
  for (int r = 0; r < 4; r++){
    int idx = tid + r * 256;
    int row = idx >> 3, ch = idx & 7;
    int sg = t0 - 64 + row; sg = sg < 0 ? 0 : sg;
    uint4 v = *(const uint4*)(qbase + 768 + (size_t)sg * 2304 + ch * 8);
    *(uint4*)&Ks[row * 72 + ch * 8] = v;
  }
  // ---- stage V transposed (s-major lane assignment -> 2-way LDS writes)
  #pragma unroll
  for (int r = 0; r < 4; r++){
    int idx = tid + r * 256;
    int s = idx & 127, ch = idx >> 7;
    int sg = t0 - 64 + s; sg = sg < 0 ? 0 : sg;
    uint4 v = *(const uint4*)(qbase + 1536 + (size_t)sg * 2304 + ch * 8);
    unsigned short tmp[8];
    *(uint4*)tmp = v;
    #pragma unroll
    for (int j = 0; j < 8; j++)
      Vt[(ch * 8 + j) * 136 + s] = tmp[j];
  }
  __syncthreads();

  // ---- S = Q K^T for 16 own rows x 128 cols (8 col-fragments x 2 k-steps)
  f32x4 sc[8];
  #pragma unroll
  for (int sj = 0; sj < 8; sj++) sc[sj] = (f32x4){0.f, 0.f, 0.f, 0.f};
  #pragma unroll
  for (int kk = 0; kk < 2; kk++){
    bf16x8 aq = *(const bf16x8*)&Qs[(wid * 16 + la) * 72 + kk * 32 + hi * 8];
    #pragma unroll
    for (int sj = 0; sj < 8; sj++){
      bf16x8 bk = *(const bf16x8*)&Ks[(sj * 16 + la) * 72 + kk * 32 + hi * 8];
      sc[sj] = __builtin_amdgcn_mfma_f32_16x16x32_bf16(aq, bk, sc[sj], 0, 0, 0);
    }
  }

  // ---- masked in-register softmax (row = wid*16 + hi*4 + r2, col = sj*16 + la)
  float inv[4];
  #pragma unroll
  for (int r2 = 0; r2 < 4; r2++){
    int row = wid * 16 + hi * 4 + r2;
    float mx = -1e30f;
    #pragma unroll
    for (int sj = 0; sj < 8; sj++){
      int sl = sj * 16 + la;
      bool valid = (sl >= row + 1) && (sl <= row + 64) && (t0 - 64 + sl >= 0);
      float sv = valid ? sc[sj][r2] * 0.125f : -1e30f;
      sc[sj][r2] = sv;
      mx = fmaxf(mx, sv);
    }
    #pragma unroll
    for (int o = 8; o >= 1; o >>= 1) mx = fmaxf(mx, __shfl_xor(mx, o));
    float sum = 0.0f;
    #pragma unroll
    for (int sj = 0; sj < 8; sj++){
      float p = __expf(sc[sj][r2] - mx);
      sc[sj][r2] = p;
      sum += p;
    }
    #pragma unroll
    for (int o = 8; o >= 1; o >>= 1) sum += __shfl_xor(sum, o);
    inv[r2] = 1.0f / sum;
  }

  // ---- P -> LDS (bf16), per-wave region
  unsigned short* myP = Ps[wid];
  #pragma unroll
  for (int sj = 0; sj < 8; sj++)
    #pragma unroll
    for (int r2 = 0; r2 < 4; r2++)
      myP[(hi * 4 + r2) * 136 + sj * 16 + la] = f2b(sc[sj][r2]);

  __syncthreads();

  // ---- O = P V  (A = P[16x128], B^T = Vt[64x128], 4 n-frags x 4 k-steps)
  f32x4 oacc[4];
  #pragma unroll
  for (int nj = 0; nj < 4; nj++) oacc[nj] = (f32x4){0.f, 0.f, 0.f, 0.f};
  #pragma unroll
  for (int ks = 0; ks < 4; ks++){
    bf16x8 ap = *(const bf16x8*)&myP[la * 136 + ks * 32 + hi * 8];
    #pragma unroll
    for (int nj = 0; nj < 4; nj++){
      bf16x8 bv = *(const bf16x8*)&Vt[(nj * 16 + la) * 136 + ks * 32 + hi * 8];
      oacc[nj] = __builtin_amdgcn_mfma_f32_16x16x32_bf16(ap, bv, oacc[nj], 0, 0, 0);
    }
  }

  // ---- write O (bf16, head-concat layout), scaled by 1/rowsum
  unsigned short* obase = attn + (size_t)(b * 1024 + t0) * 768 + h * 64;
  #pragma unroll
  for (int nj = 0; nj < 4; nj++)
    #pragma unroll
    for (int r2 = 0; r2 < 4; r2++){
      int row = wid * 16 + hi * 4 + r2;
      obase[(size_t)row * 768 + nj * 16 + la] = f2b(oacc[nj][r2] * inv[r2]);
    }
}

__global__ void aux_k(float* p){ if (threadIdx.x == 0) p[0] = 0.0f; }

// ----------------------------------------------------------------------------------
extern "C" void kernel_launch(void* const* d_in, const int* in_sizes, int n_in,
                              void* d_out, int out_size, void* d_ws, size_t ws_size,
                              hipStream_t stream)
{
  const float* x      = (const float*)d_in[0];
  const float* w_q    = (const float*)d_in[1];
  const float* w_k    = (const float*)d_in[2];
  const float* w_v    = (const float*)d_in[3];
  const float* w_proj = (const float*)d_in[4];
  const float* b_proj = (const float*)d_in[5];
  const float* w_ff1  = (const float*)d_in[6];
  const float* b_ff1  = (const float*)d_in[7];
  const float* w_ff2  = (const float*)d_in[8];
  const float* b_ff2  = (const float*)d_in[9];
  const float* g1     = (const float*)d_in[10];
  const float* g2     = (const float*)d_in[11];
  float* out = (float*)d_out;

  char* ws = (char*)d_ws;
  size_t off = 0;
  auto alloc = [&](size_t bytes){ size_t r = off; off += (bytes + 255) & ~(size_t)255; return r; };
  const size_t BT = 8 * 1024;  // 8192 rows

  unsigned short* h     = (unsigned short*)(ws + alloc(BT * 768 * 2));   // reused for attn out
  unsigned short* qkv   = (unsigned short*)(ws + alloc(BT * 3072 * 2));  // reused for ffa
  unsigned short* x2b   = (unsigned short*)(ws + alloc(BT * 768 * 2));   // x2 as bf16
  unsigned short* h2    = (unsigned short*)(ws + alloc(BT * 768 * 2));
  unsigned short* WqkvT = (unsigned short*)(ws + alloc(2304 * 768 * 2));
  unsigned short* WprojT= (unsigned short*)(ws + alloc(768 * 768 * 2));
  unsigned short* Wff1T = (unsigned short*)(ws + alloc(3072 * 768 * 2));
  unsigned short* Wff2T = (unsigned short*)(ws + alloc(768 * 3072 * 2));
  unsigned short* attn  = h;     // h dead after QKV GEMM
  unsigned short* ffa   = qkv;   // qkv dead after attention

  // all weights -> bf16 transposed, ONE launch
  transpose_all<<<6912, 256, 0, stream>>>(w_q, w_k, w_v, w_proj, w_ff1, w_ff2,
                                          WqkvT, WprojT, Wff1T, Wff2T);

  // h = rmsnorm(x, g1)   (f32 input)
  rmsnorm_k<true><<<2048, 256, 0, stream>>>(x, g1, h);

  // qkv = h @ [Wq|Wk|Wv]   (M=8192, N=2304, K=768) — BM=64, 2304 tiles, TPB=3
  gemm_db<64,3,false,false,0,false><<<768, 256, 0, stream>>>(h, WqkvT, nullptr, nullptr, qkv, 8192, 2304, 768);

  // sliding-window attention -> attn (bf16, [B*T][768] head-concat layout)
  attn_k<<<8 * 12 * 16, 256, 0, stream>>>(qkv, attn);

  // x2b = bf16(x + attn @ Wproj + b_proj) — BM=64, 768 tiles, TPB=1, f32 residual
  gemm_db<64,1,true,false,1,false><<<768, 256, 0, stream>>>(attn, WprojT, b_proj, x, x2b, 8192, 768, 768);

  // h2 = rmsnorm(x2b, g2)   (bf16 input)
  rmsnorm_k<false><<<2048, 256, 0, stream>>>(x2b, g2, h2);

  // ffa = gelu(h2 @ Wff1 + b_ff1)   (M=8192, N=3072, K=768) — BM=128, TPB=3
  gemm_db<128,3,true,true,0,false><<<512, 256, 0, stream>>>(h2, Wff1T, b_ff1, nullptr, ffa, 8192, 3072, 768);

  // out = x2b + ffa @ Wff2 + b_ff2   (fp32 out; bf16 residual) — BM=64, TPB=1
  gemm_db<64,1,true,false,2,true><<<768, 256, 0, stream>>>(ffa, Wff2T, b_ff2, x2b, out, 8192, 768, 3072);

  // aux scalar
  aux_k<<<1, 64, 0, stream>>>(out + 6291456);
}